// Round 1
// baseline (2686.119 us; speedup 1.0000x reference)
//
#include <hip/hip_runtime.h>
#include <hip/hip_bf16.h>

// DualPathModule: 2 layers x (t-path, b-path) Mamba2.
// Shapes: HID=256, DIN=512, NHEADS=8, HEADP=64, DSTATE=64, CONVDIM=640, PROJ=1160
// t-path: 124 seqs x L=192 (strided in x); b-path: 384 seqs x L=62 (contiguous).
// M = 23808 tokens per invocation.

#define MTOK   23808
#define PROJ   1160

__device__ __forceinline__ float wave_sum64(float v) {
#pragma unroll
  for (int off = 32; off; off >>= 1) v += __shfl_xor(v, off, 64);
  return v;
}

// token m of t-path (seq = b*62+nb, time tt) -> flat offset in x (B,T,NB,H)
__device__ __forceinline__ long t_base(int m) {
  int seq = m / 192, tt = m - seq * 192;
  int b = seq / 62, nb = seq - b * 62;
  return ((long)((b * 192 + tt) * 62 + nb)) * 256;
}

// ---------------- K1: gather + rmsnorm over H=256 -> bufn[M x 256]
template <bool TPATH>
__global__ __launch_bounds__(256) void k_rmsnorm_in(const float* __restrict__ xio,
                                                    const float* __restrict__ w,
                                                    float* __restrict__ outb) {
  int m = blockIdx.x * 4 + (threadIdx.x >> 6);
  int lane = threadIdx.x & 63;
  long base = TPATH ? t_base(m) : (long)m * 256;
  float4 v = *(const float4*)(xio + base + lane * 4);
  float ss = v.x * v.x + v.y * v.y + v.z * v.z + v.w * v.w;
  ss = wave_sum64(ss);
  float sc = rsqrtf(ss * (1.f / 256.f) + 1e-6f);
  float4 wv = *(const float4*)(w + lane * 4);
  float4 o = make_float4(v.x * sc * wv.x, v.y * sc * wv.y, v.z * sc * wv.z, v.w * sc * wv.w);
  *(float4*)(outb + (long)m * 256 + lane * 4) = o;
}

// ---------------- GEMM: C[M x N] = A[M x K] * W[K x N], 64x64 tile, 4x4 micro
// EPI: 0 = plain store to C (ldc). 1 = t-path residual add into out. 2 = b-path residual.
template <int EPI>
__global__ __launch_bounds__(256) void gemm64(const float* __restrict__ A,
                                              const float* __restrict__ W,
                                              float* __restrict__ C,
                                              int N, int K, int ldw, int ldc) {
  __shared__ float As[16][68];  // [k][m] (transposed), padded for b128 alignment
  __shared__ float Ws[16][64];  // [k][n]
  int t = threadIdx.x;
  int col0 = blockIdx.x * 64, row0 = blockIdx.y * 64;
  int tx = t & 15, ty = t >> 4;
  int am = t >> 2, ak = (t & 3) * 4;
  int wk = t >> 4, wn = (t & 15) * 4;
  float acc[4][4] = {};
  for (int k0 = 0; k0 < K; k0 += 16) {
    float4 a4 = *(const float4*)(A + (long)(row0 + am) * K + k0 + ak);
    float4 w4;
    int nc = col0 + wn;
    const float* wrow = W + (long)(k0 + wk) * ldw;
    if (nc + 3 < N) {
      w4 = *(const float4*)(wrow + nc);
    } else {
      w4.x = nc + 0 < N ? wrow[nc + 0] : 0.f;
      w4.y = nc + 1 < N ? wrow[nc + 1] : 0.f;
      w4.z = nc + 2 < N ? wrow[nc + 2] : 0.f;
      w4.w = nc + 3 < N ? wrow[nc + 3] : 0.f;
    }
    __syncthreads();  // previous iter's compute done before overwrite
    As[ak + 0][am] = a4.x; As[ak + 1][am] = a4.y; As[ak + 2][am] = a4.z; As[ak + 3][am] = a4.w;
    *(float4*)&Ws[wk][wn] = w4;
    __syncthreads();
#pragma unroll
    for (int k = 0; k < 16; ++k) {
      float4 av = *(const float4*)&As[k][ty * 4];
      float4 bv = *(const float4*)&Ws[k][tx * 4];
      acc[0][0] += av.x * bv.x; acc[0][1] += av.x * bv.y; acc[0][2] += av.x * bv.z; acc[0][3] += av.x * bv.w;
      acc[1][0] += av.y * bv.x; acc[1][1] += av.y * bv.y; acc[1][2] += av.y * bv.z; acc[1][3] += av.y * bv.w;
      acc[2][0] += av.z * bv.x; acc[2][1] += av.z * bv.y; acc[2][2] += av.z * bv.z; acc[2][3] += av.z * bv.w;
      acc[3][0] += av.w * bv.x; acc[3][1] += av.w * bv.y; acc[3][2] += av.w * bv.z; acc[3][3] += av.w * bv.w;
    }
  }
#pragma unroll
  for (int i = 0; i < 4; ++i) {
    int m = row0 + ty * 4 + i;
    int n0 = col0 + tx * 4;
    if (EPI == 0) {
      float* cp = C + (long)m * ldc + n0;
      if (n0 + 3 < N) {
        *(float4*)cp = make_float4(acc[i][0], acc[i][1], acc[i][2], acc[i][3]);
      } else {
#pragma unroll
        for (int j = 0; j < 4; ++j)
          if (n0 + j < N) cp[j] = acc[i][j];
      }
    } else {
      long base = (EPI == 1) ? t_base(m) : (long)m * 256;
      float* cp = C + base + n0;
      cp[0] += acc[i][0]; cp[1] += acc[i][1]; cp[2] += acc[i][2]; cp[3] += acc[i][3];
    }
  }
}

// ---------------- causal depthwise conv(K=4) + silu over zx cols [512,1152) -> xBC[M x 640]
__global__ __launch_bounds__(256) void k_conv(const float* __restrict__ zx,
                                              const float* __restrict__ Wc,
                                              const float* __restrict__ bc,
                                              float* __restrict__ xBC, int L) {
  int idx = blockIdx.x * 256 + threadIdx.x;
  if (idx >= MTOK * 640) return;
  int m = idx / 640, c = idx - m * 640;
  int tpos = m % L;
  float acc = bc[c];
#pragma unroll
  for (int k = 0; k < 4; ++k) {
    int tt = tpos - 3 + k;
    if (tt >= 0) acc += Wc[c * 4 + k] * zx[(long)(m - 3 + k) * PROJ + 512 + c];
  }
  xBC[(long)m * 640 + c] = acc / (1.f + expf(-acc));  // silu
}

// ---------------- dt = softplus(zx[:,1152+h] + dt_bias[h]) -> dt[M x 8]
__global__ __launch_bounds__(256) void k_dt(const float* __restrict__ zx,
                                            const float* __restrict__ dtb,
                                            float* __restrict__ dt) {
  int idx = blockIdx.x * 256 + threadIdx.x;
  if (idx >= MTOK * 8) return;
  int m = idx >> 3, h = idx & 7;
  float v = zx[(long)m * PROJ + 1152 + h] + dtb[h];
  dt[idx] = (v > 20.f) ? v : log1pf(expf(v));
}

// ---------------- per (seq, head) inclusive cumsum of dt*A -> cum[M x 8]
__global__ __launch_bounds__(256) void k_cum(const float* __restrict__ dt,
                                             const float* __restrict__ A_log,
                                             float* __restrict__ cum, int nseq, int L) {
  int sid = blockIdx.x * 256 + threadIdx.x;
  if (sid >= nseq * 8) return;
  int seq = sid >> 3, h = sid & 7;
  float Ah = -expf(A_log[h]);
  float run = 0.f;
  for (int tt = 0; tt < L; ++tt) {
    int m = seq * L + tt;
    run += dt[m * 8 + h] * Ah;
    cum[m * 8 + h] = run;
  }
}

// ---------------- SSD: y[l,h,p] = sum_s CB[l,s]*w(l,s,h)*dt[s]*x[s,h,p], fwd+rev fused
// fwd (s<=l): exp(cum_l - cum_s); rev (s>=l): exp(cumP_s - cumP_l), cumP = cum - dt*A.
// Diagonal s==l counted twice (matches reference).
template <int L>
__global__ __launch_bounds__(256) void k_ssd(const float* __restrict__ xBC,
                                             const float* __restrict__ dt,
                                             const float* __restrict__ cum,
                                             const float* __restrict__ A_log,
                                             float* __restrict__ y) {
  constexpr int NCH = (L + 63) / 64;
  int seq = blockIdx.x, lt = blockIdx.y, h = blockIdx.z;
  __shared__ float ClT[64][68];  // [n][l]
  __shared__ float Bt[64][65];   // [n][s]
  __shared__ float xs[64][64];   // [s][p]
  __shared__ float sc[64][68];   // [l][s]
  __shared__ float cum_l[64], cumP_l[64], cum_s[64], cumP_s[64], dts[64];
  int t = threadIdx.x;
  float Ah = -expf(A_log[h]);

  for (int e = t; e < 1024; e += 256) {
    int ll = e >> 4, q = e & 15;
    int lg = lt * 64 + ll;
    float4 v = make_float4(0.f, 0.f, 0.f, 0.f);
    if (lg < L) v = *(const float4*)(xBC + (long)(seq * L + lg) * 640 + 576 + q * 4);
    ClT[q * 4 + 0][ll] = v.x; ClT[q * 4 + 1][ll] = v.y;
    ClT[q * 4 + 2][ll] = v.z; ClT[q * 4 + 3][ll] = v.w;
  }
  if (t < 64) {
    int lg = lt * 64 + t;
    float cv = 0.f, dv = 0.f;
    if (lg < L) { int m = seq * L + lg; cv = cum[m * 8 + h]; dv = dt[m * 8 + h]; }
    cum_l[t] = cv; cumP_l[t] = cv - dv * Ah;
  }

  float acc[16];
#pragma unroll
  for (int i = 0; i < 16; ++i) acc[i] = 0.f;
  int sg = t & 63, g = t >> 6;

  for (int c = 0; c < NCH; ++c) {
    __syncthreads();
    for (int e = t; e < 1024; e += 256) {
      int ssi = e >> 4, q = e & 15;
      int sgl = c * 64 + ssi;
      float4 bv = make_float4(0.f, 0.f, 0.f, 0.f), xv = make_float4(0.f, 0.f, 0.f, 0.f);
      if (sgl < L) {
        const float* base = xBC + (long)(seq * L + sgl) * 640;
        bv = *(const float4*)(base + 512 + q * 4);
        xv = *(const float4*)(base + h * 64 + q * 4);
      }
      Bt[q * 4 + 0][ssi] = bv.x; Bt[q * 4 + 1][ssi] = bv.y;
      Bt[q * 4 + 2][ssi] = bv.z; Bt[q * 4 + 3][ssi] = bv.w;
      *(float4*)&xs[ssi][q * 4] = xv;
    }
    if (t < 64) {
      int sgl = c * 64 + t;
      float cv = 0.f, dv = 0.f;
      if (sgl < L) { int m = seq * L + sgl; cv = cum[m * 8 + h]; dv = dt[m * 8 + h]; }
      cum_s[t] = cv; cumP_s[t] = cv - dv * Ah; dts[t] = dv;
    }
    __syncthreads();

    // phase A: dots CB[l, sg] for l = g*16 + i
    float dot[16];
#pragma unroll
    for (int i = 0; i < 16; ++i) dot[i] = 0.f;
    for (int n = 0; n < 64; ++n) {
      float bn = Bt[n][sg];
      const float* cr = &ClT[n][g * 16];
      float4 c0 = *(const float4*)(cr + 0);
      float4 c1 = *(const float4*)(cr + 4);
      float4 c2 = *(const float4*)(cr + 8);
      float4 c3 = *(const float4*)(cr + 12);
      dot[0] += c0.x * bn;  dot[1] += c0.y * bn;  dot[2] += c0.z * bn;  dot[3] += c0.w * bn;
      dot[4] += c1.x * bn;  dot[5] += c1.y * bn;  dot[6] += c1.z * bn;  dot[7] += c1.w * bn;
      dot[8] += c2.x * bn;  dot[9] += c2.y * bn;  dot[10] += c2.z * bn; dot[11] += c2.w * bn;
      dot[12] += c3.x * bn; dot[13] += c3.y * bn; dot[14] += c3.z * bn; dot[15] += c3.w * bn;
    }
    int sgl = c * 64 + sg;
#pragma unroll
    for (int i = 0; i < 16; ++i) {
      int li = g * 16 + i;
      int lg = lt * 64 + li;
      float wgt = 0.f;
      if (lg < L && sgl < L) {
        if (sgl <= lg) wgt += expf(cum_l[li] - cum_s[sg]);
        if (sgl >= lg) wgt += expf(cumP_s[sg] - cumP_l[li]);
      }
      sc[li][sg] = dot[i] * wgt * dts[sg];
    }
    __syncthreads();

    // phase B: acc[i] += sum_s sc[g*16+i][s] * xs[s][p],  p = sg
    for (int s4 = 0; s4 < 16; ++s4) {
      float xv0 = xs[s4 * 4 + 0][sg];
      float xv1 = xs[s4 * 4 + 1][sg];
      float xv2 = xs[s4 * 4 + 2][sg];
      float xv3 = xs[s4 * 4 + 3][sg];
#pragma unroll
      for (int i = 0; i < 16; ++i) {
        float4 s4v = *(const float4*)&sc[g * 16 + i][s4 * 4];
        acc[i] += s4v.x * xv0 + s4v.y * xv1 + s4v.z * xv2 + s4v.w * xv3;
      }
    }
  }

#pragma unroll
  for (int i = 0; i < 16; ++i) {
    int lg = lt * 64 + g * 16 + i;
    if (lg < L) y[(long)(seq * L + lg) * 512 + h * 64 + sg] = acc[i];
  }
}

// ---------------- gate: y = rmsnorm((y + D*xh) * silu(z)) * gn_w, in-place over [M x 512]
__global__ __launch_bounds__(256) void k_gate(float* __restrict__ y,
                                              const float* __restrict__ zx,
                                              const float* __restrict__ xBC,
                                              const float* __restrict__ Dp,
                                              const float* __restrict__ gnw) {
  int m = blockIdx.x * 4 + (threadIdx.x >> 6);
  int lane = threadIdx.x & 63;
  int d0 = lane * 4, d1 = 256 + lane * 4;
  float* yp = y + (long)m * 512;
  const float* xp = xBC + (long)m * 640;
  const float* zp = zx + (long)m * PROJ;
  float4 ya = *(const float4*)(yp + d0);
  float4 yb = *(const float4*)(yp + d1);
  float4 xa = *(const float4*)(xp + d0);
  float4 xb = *(const float4*)(xp + d1);
  float4 za = *(const float4*)(zp + d0);
  float4 zb = *(const float4*)(zp + d1);
  float Da = Dp[lane >> 4];
  float Db = Dp[4 + (lane >> 4)];
  float g[8];
  g[0] = (ya.x + Da * xa.x) * za.x / (1.f + expf(-za.x));
  g[1] = (ya.y + Da * xa.y) * za.y / (1.f + expf(-za.y));
  g[2] = (ya.z + Da * xa.z) * za.z / (1.f + expf(-za.z));
  g[3] = (ya.w + Da * xa.w) * za.w / (1.f + expf(-za.w));
  g[4] = (yb.x + Db * xb.x) * zb.x / (1.f + expf(-zb.x));
  g[5] = (yb.y + Db * xb.y) * zb.y / (1.f + expf(-zb.y));
  g[6] = (yb.z + Db * xb.z) * zb.z / (1.f + expf(-zb.z));
  g[7] = (yb.w + Db * xb.w) * zb.w / (1.f + expf(-zb.w));
  float ss = 0.f;
#pragma unroll
  for (int i = 0; i < 8; ++i) ss += g[i] * g[i];
  ss = wave_sum64(ss);
  float scl = rsqrtf(ss * (1.f / 512.f) + 1e-6f);
  float4 wa = *(const float4*)(gnw + d0);
  float4 wb = *(const float4*)(gnw + d1);
  *(float4*)(yp + d0) = make_float4(g[0] * scl * wa.x, g[1] * scl * wa.y,
                                    g[2] * scl * wa.z, g[3] * scl * wa.w);
  *(float4*)(yp + d1) = make_float4(g[4] * scl * wb.x, g[5] * scl * wb.y,
                                    g[6] * scl * wb.z, g[7] * scl * wb.w);
}

extern "C" void kernel_launch(void* const* d_in, const int* in_sizes, int n_in,
                              void* d_out, int out_size, void* d_ws, size_t ws_size,
                              hipStream_t stream) {
  (void)in_sizes; (void)n_in; (void)out_size; (void)ws_size;
  const float* x = (const float*)d_in[0];
  float* out = (float*)d_out;
  float* ws = (float*)d_ws;
  const long M = MTOK;

  float* zx   = ws;                       // M*1160
  float* bufn = zx + M * PROJ;            // M*256
  float* xbc  = bufn + M * 256;           // M*640
  float* dtb_ = xbc + M * 640;            // M*8
  float* cumb = dtb_ + M * 8;             // M*8
  float* yb   = cumb + M * 8;             // M*512
  // total: M*2584 floats = 246 MB

  hipMemcpyAsync(out, x, (size_t)M * 256 * sizeof(float), hipMemcpyDeviceToDevice, stream);

  for (int layer = 0; layer < 2; ++layer) {
    for (int path = 0; path < 2; ++path) {
      const float* const* P = (const float* const*)(d_in + 1 + path * 9);
      const float* nw     = P[0] + layer * 256;
      const float* Win    = P[1] + (long)layer * 256 * PROJ;
      const float* Wc     = P[2] + layer * 640 * 4;
      const float* bc     = P[3] + layer * 640;
      const float* dtbias = P[4] + layer * 8;
      const float* Alog   = P[5] + layer * 8;
      const float* Dp     = P[6] + layer * 8;
      const float* gnw    = P[7] + layer * 512;
      const float* Wout   = P[8] + (long)layer * 512 * 256;
      int L = (path == 0) ? 192 : 62;
      int nseq = (path == 0) ? 124 : 384;

      if (path == 0) k_rmsnorm_in<true><<<MTOK / 4, 256, 0, stream>>>(out, nw, bufn);
      else           k_rmsnorm_in<false><<<MTOK / 4, 256, 0, stream>>>(out, nw, bufn);

      gemm64<0><<<dim3((PROJ + 63) / 64, MTOK / 64), 256, 0, stream>>>(
          bufn, Win, zx, PROJ, 256, PROJ, PROJ);

      k_conv<<<(MTOK * 640 + 255) / 256, 256, 0, stream>>>(zx, Wc, bc, xbc, L);
      k_dt<<<(MTOK * 8 + 255) / 256, 256, 0, stream>>>(zx, dtbias, dtb_);
      k_cum<<<(nseq * 8 + 255) / 256, 256, 0, stream>>>(dtb_, Alog, cumb, nseq, L);

      if (path == 0) k_ssd<192><<<dim3(nseq, 3, 8), 256, 0, stream>>>(xbc, dtb_, cumb, Alog, yb);
      else           k_ssd<62><<<dim3(nseq, 1, 8), 256, 0, stream>>>(xbc, dtb_, cumb, Alog, yb);

      k_gate<<<MTOK / 4, 256, 0, stream>>>(yb, zx, xbc, Dp, gnw);

      if (path == 0) gemm64<1><<<dim3(4, MTOK / 64), 256, 0, stream>>>(yb, Wout, out, 256, 512, 256, 0);
      else           gemm64<2><<<dim3(4, MTOK / 64), 256, 0, stream>>>(yb, Wout, out, 256, 512, 256, 0);
    }
  }
}

// Round 2
// 1273.840 us; speedup vs baseline: 2.1087x; 2.1087x over previous
//
#include <hip/hip_runtime.h>
#include <hip/hip_bf16.h>

// DualPathModule: 2 layers x (t-path, b-path) Mamba2, bf16-MFMA version.
// HID=256, DIN=512, NHEADS=8, HEADP=64, DSTATE=64, CONVDIM=640, PROJ=1160 (padded 1280)
// t-path: 124 seqs x L=192 (strided in x); b-path: 384 seqs x L=62. M=23808.

#define MTOK   23808
#define PROJP  1280   // padded projection dim (row stride of zx, WinT rows)

typedef __attribute__((ext_vector_type(8))) short short8v;
typedef __attribute__((ext_vector_type(4))) short short4v;
typedef __attribute__((ext_vector_type(4))) float f32x4;

__device__ __forceinline__ float wave_sum64(float v) {
#pragma unroll
  for (int off = 32; off; off >>= 1) v += __shfl_xor(v, off, 64);
  return v;
}

__device__ __forceinline__ short f2bf(float f) {
  union { float f; unsigned u; } v; v.f = f;
  unsigned r = (v.u + 0x7fffu + ((v.u >> 16) & 1u)) >> 16;  // RNE
  return (short)r;
}
__device__ __forceinline__ float bf2f(short s) {
  union { unsigned u; float f; } v; v.u = ((unsigned)(unsigned short)s) << 16; return v.f;
}

// token m of t-path (seq = b*62+nb, time tt) -> flat offset in x (B,T,NB,H)
__device__ __forceinline__ long t_base(int m) {
  int seq = m / 192, tt = m - seq * 192;
  int b = seq / 62, nb = seq - b * 62;
  return ((long)((b * 192 + tt) * 62 + nb)) * 256;
}

// ---------------- weight transpose+cvt: dst[z][n][k] = src_z[k][n], n>=N zero-padded
__global__ __launch_bounds__(256) void k_wt(const float* __restrict__ tW,
                                            const float* __restrict__ bW,
                                            short* __restrict__ dst, int K, int N, int NP) {
  int z = blockIdx.z;
  const float* src = (z >> 1 ? bW : tW) + (long)(z & 1) * K * N;
  short* d = dst + (long)z * NP * K;
  int idx = blockIdx.x * 256 + threadIdx.x;
  if (idx >= NP * K) return;
  int n = idx / K, k = idx - n * K;
  d[idx] = (n < N) ? f2bf(src[(long)k * N + n]) : (short)0;
}

// ---------------- gather + rmsnorm over H=256 -> bufn[M x 256] bf16
template <bool TPATH>
__global__ __launch_bounds__(256) void k_rmsnorm_in(const float* __restrict__ xio,
                                                    const float* __restrict__ w,
                                                    short* __restrict__ outb) {
  int m = blockIdx.x * 4 + (threadIdx.x >> 6);
  int lane = threadIdx.x & 63;
  long base = TPATH ? t_base(m) : (long)m * 256;
  float4 v = *(const float4*)(xio + base + lane * 4);
  float ss = v.x * v.x + v.y * v.y + v.z * v.z + v.w * v.w;
  ss = wave_sum64(ss);
  float sc = rsqrtf(ss * (1.f / 256.f) + 1e-6f);
  float4 wv = *(const float4*)(w + lane * 4);
  short4v o;
  o[0] = f2bf(v.x * sc * wv.x); o[1] = f2bf(v.y * sc * wv.y);
  o[2] = f2bf(v.z * sc * wv.z); o[3] = f2bf(v.w * sc * wv.w);
  *(short4v*)(outb + (long)m * 256 + lane * 4) = o;
}

// ---------------- MFMA GEMM: C[M x N] = A[M x K] * WT[N x K]^T  (bf16 in, f32 acc)
// block 128x128 (4 waves 2x2, each 64x64). EPI: 0 plain f32 store (ldc),
// 1 t-path residual add into out, 2 b-path residual add.
template <int EPI>
__global__ __launch_bounds__(256) void gemm_mfma(const short* __restrict__ A,
                                                 const short* __restrict__ WT,
                                                 float* __restrict__ C,
                                                 int K, int ldc) {
  int w = threadIdx.x >> 6, lane = threadIdx.x & 63;
  int m0 = blockIdx.y * 128 + (w >> 1) * 64;
  int n0 = blockIdx.x * 128 + (w & 1) * 64;
  int lr = lane & 15, lg = lane >> 4;
  f32x4 acc[4][4];
#pragma unroll
  for (int i = 0; i < 4; ++i)
#pragma unroll
    for (int j = 0; j < 4; ++j) acc[i][j] = (f32x4){0.f, 0.f, 0.f, 0.f};
  const short* Ap = A + (long)(m0 + lr) * K + lg * 8;
  const short* Bp = WT + (long)(n0 + lr) * K + lg * 8;
#pragma unroll 2
  for (int k0 = 0; k0 < K; k0 += 32) {
    short8v a[4], b[4];
#pragma unroll
    for (int f = 0; f < 4; ++f) {
      a[f] = *(const short8v*)(Ap + (long)f * 16 * K + k0);
      b[f] = *(const short8v*)(Bp + (long)f * 16 * K + k0);
    }
#pragma unroll
    for (int i = 0; i < 4; ++i)
#pragma unroll
      for (int j = 0; j < 4; ++j)
        acc[i][j] = __builtin_amdgcn_mfma_f32_16x16x32_bf16(a[i], b[j], acc[i][j], 0, 0, 0);
  }
#pragma unroll
  for (int i = 0; i < 4; ++i)
#pragma unroll
    for (int j = 0; j < 4; ++j)
#pragma unroll
      for (int r = 0; r < 4; ++r) {
        int m = m0 + i * 16 + lg * 4 + r;
        int n = n0 + j * 16 + lr;
        if (EPI == 0) {
          C[(long)m * ldc + n] = acc[i][j][r];
        } else {
          long base = (EPI == 1) ? t_base(m) : (long)m * 256;
          C[base + n] += acc[i][j][r];
        }
      }
}

// ---------------- causal depthwise conv(K=4) + silu -> xBC[M x 640] bf16
__global__ __launch_bounds__(256) void k_conv(const float* __restrict__ zx,
                                              const float* __restrict__ Wc,
                                              const float* __restrict__ bc,
                                              short* __restrict__ xBC, int L) {
  int idx = blockIdx.x * 256 + threadIdx.x;
  if (idx >= MTOK * 640) return;
  int m = idx / 640, c = idx - m * 640;
  int tpos = m % L;
  float acc = bc[c];
#pragma unroll
  for (int k = 0; k < 4; ++k) {
    int tt = tpos - 3 + k;
    if (tt >= 0) acc += Wc[c * 4 + k] * zx[(long)(m - 3 + k) * PROJP + 512 + c];
  }
  xBC[(long)m * 640 + c] = f2bf(acc / (1.f + __expf(-acc)));
}

// ---------------- fused softplus(dt) + per-(seq,head) inclusive scan of dt*A
__global__ __launch_bounds__(256) void k_scan(const float* __restrict__ zx,
                                              const float* __restrict__ dtbias,
                                              const float* __restrict__ A_log,
                                              float* __restrict__ dtb,
                                              float* __restrict__ cumb,
                                              int nseq, int L) {
  int wid = blockIdx.x * 4 + (threadIdx.x >> 6);
  if (wid >= nseq * 8) return;
  int seq = wid >> 3, h = wid & 7, lane = threadIdx.x & 63;
  float Ah = -__expf(A_log[h]);
  float bias = dtbias[h];
  float run = 0.f;
  for (int t0 = 0; t0 < L; t0 += 64) {
    int tt = t0 + lane;
    float d = 0.f;
    if (tt < L) {
      float v = zx[((long)seq * L + tt) * PROJP + 1152 + h] + bias;
      d = (v > 20.f) ? v : log1pf(__expf(v));
    }
    float s = d * Ah;
#pragma unroll
    for (int off = 1; off < 64; off <<= 1) {
      float o = __shfl_up(s, off, 64);
      if (lane >= off) s += o;
    }
    if (tt < L) {
      long m = (long)seq * L + tt;
      dtb[m * 8 + h] = d;
      cumb[m * 8 + h] = run + s;
    }
    run += __shfl(s, 63, 64);
  }
}

// ---------------- x transpose: xT[(seq*8+h)*64 + p][LP] = x[s][h*64+p], zero-padded s>=L
template <int L>
__global__ __launch_bounds__(256) void k_xt(const short* __restrict__ xbc,
                                            short* __restrict__ xT) {
  constexpr int LP = (L + 63) & ~63;
  int seq = blockIdx.x, h = blockIdx.y, st = blockIdx.z;
  __shared__ short tile[64][72];
  int t = threadIdx.x;
  for (int e = t; e < 512; e += 256) {
    int s = e >> 3, p8 = (e & 7) * 8;
    int sg = st * 64 + s;
    union { short8v v; short a[8]; } u;
    if (sg < L) u.v = *(const short8v*)(xbc + ((long)seq * L + sg) * 640 + h * 64 + p8);
    else {
#pragma unroll
      for (int j = 0; j < 8; ++j) u.a[j] = 0;
    }
    *(short8v*)&tile[s][p8] = u.v;
  }
  __syncthreads();
  for (int e = t; e < 512; e += 256) {
    int p = e >> 3, s8 = (e & 7) * 8;
    union { short8v v; short a[8]; } u;
#pragma unroll
    for (int j = 0; j < 8; ++j) u.a[j] = tile[s8 + j][p];
    *(short8v*)(xT + ((long)(seq * 8 + h) * 64 + p) * LP + st * 64 + s8) = u.v;
  }
}

// ---------------- SSD via MFMA. Block = (seq, l-tile); 4 waves, each 2 heads.
// Phase A: CB[64x64] = C_tile . B_tile^T (operands straight from global bf16 xBC).
// Decay+dt applied in f32 acc regs -> P bf16 -> per-wave swizzled LDS.
// Phase B: y_h = P . X_h (A from LDS, B from global xT). Diagonal counted twice.
template <int L, int NCH>
__global__ __launch_bounds__(256) void k_ssd2(const short* __restrict__ xbc,
                                              const short* __restrict__ xT,
                                              const float* __restrict__ dtb,
                                              const float* __restrict__ cumb,
                                              const float* __restrict__ A_log,
                                              short* __restrict__ y) {
  constexpr int LP = (L + 63) & ~63;
  int seq = blockIdx.x, lt = blockIdx.y;
  int w = threadIdx.x >> 6, lane = threadIdx.x & 63;
  int lr = lane & 15, lg = lane >> 4;
  int l0 = lt * 64;

  __shared__ float s_cum_l[8][64], s_dt_l[8][64];
  __shared__ float s_cum_s[8][64], s_dt_s[8][64];
  __shared__ short s_P[4][4096];
  short* Pw = s_P[w];

  // l-side params for all 8 heads
  for (int e = threadIdx.x; e < 512; e += 256) {
    int h = e >> 6, li = e & 63;
    int lgl = l0 + li;
    float cv = 0.f, dv = 0.f;
    if ((L % 64 == 0) || lgl < L) { long m = (long)seq * L + lgl; cv = cumb[m * 8 + h]; dv = dtb[m * 8 + h]; }
    s_cum_l[h][li] = cv; s_dt_l[h][li] = dv;
  }

  for (int hh = 0; hh < 2; ++hh) {
    int h = w * 2 + hh;
    float Ah = -__expf(A_log[h]);
    f32x4 yacc[4][4];
#pragma unroll
    for (int i = 0; i < 4; ++i)
#pragma unroll
      for (int j = 0; j < 4; ++j) yacc[i][j] = (f32x4){0.f, 0.f, 0.f, 0.f};

    for (int c = 0; c < NCH; ++c) {
      int c64 = c * 64;
      __syncthreads();
      for (int e = threadIdx.x; e < 512; e += 256) {
        int hz = e >> 6, si = e & 63;
        int sgl = c64 + si;
        float cv = 0.f, dv = 0.f;
        if ((L % 64 == 0) || sgl < L) { long m = (long)seq * L + sgl; cv = cumb[m * 8 + hz]; dv = dtb[m * 8 + hz]; }
        s_cum_s[hz][si] = cv; s_dt_s[hz][si] = dv;
      }
      __syncthreads();

      // ---- phase A: CB = C . B^T (k = dstate 64, 2 k-steps)
      f32x4 cb[4][4];
#pragma unroll
      for (int i = 0; i < 4; ++i)
#pragma unroll
        for (int j = 0; j < 4; ++j) cb[i][j] = (f32x4){0.f, 0.f, 0.f, 0.f};
      const short* Cp = xbc + ((long)seq * L + l0 + lr) * 640 + 576 + lg * 8;
      const short* Bp = xbc + ((long)seq * L + c64 + lr) * 640 + 512 + lg * 8;
#pragma unroll
      for (int ks = 0; ks < 2; ++ks) {
        short8v a[4], b[4];
#pragma unroll
        for (int f = 0; f < 4; ++f) {
          a[f] = *(const short8v*)(Cp + (long)f * 16 * 640 + ks * 32);
          b[f] = *(const short8v*)(Bp + (long)f * 16 * 640 + ks * 32);
        }
#pragma unroll
        for (int i = 0; i < 4; ++i)
#pragma unroll
          for (int j = 0; j < 4; ++j)
            cb[i][j] = __builtin_amdgcn_mfma_f32_16x16x32_bf16(a[i], b[j], cb[i][j], 0, 0, 0);
      }

      // ---- decay weighting -> P (bf16) into swizzled per-wave LDS
#pragma unroll
      for (int i = 0; i < 4; ++i) {
#pragma unroll
        for (int j = 0; j < 4; ++j) {
          int s_loc = j * 16 + lr;
          int sgl = c64 + s_loc;
          float cs = s_cum_s[h][s_loc], ds = s_dt_s[h][s_loc];
          float cps = cs - ds * Ah;
#pragma unroll
          for (int r = 0; r < 4; ++r) {
            int l_loc = i * 16 + lg * 4 + r;
            int lgl = l0 + l_loc;
            float cl = s_cum_l[h][l_loc], dl = s_dt_l[h][l_loc];
            float wgt = 0.f;
            if ((L % 64 == 0) || (lgl < L && sgl < L)) {
              if (sgl <= lgl) wgt += __expf(cl - cs);
              if (sgl >= lgl) wgt += __expf(cps - (cl - dl * Ah));
            }
            float p = cb[i][j][r] * wgt * ds;
            Pw[(l_loc * 64 + s_loc) ^ ((l_loc & 7) << 3)] = f2bf(p);
          }
        }
      }

      // ---- phase B: yacc += P . X_h  (k = s 64, 2 k-steps)
      const short* Xp = xT + ((long)(seq * 8 + h) * 64 + lr) * LP + c64 + lg * 8;
#pragma unroll
      for (int ks = 0; ks < 2; ++ks) {
        short8v a[4], b[4];
#pragma unroll
        for (int f = 0; f < 4; ++f) {
          int row = f * 16 + lr;
          int off = (row * 64 + ks * 32 + lg * 8) ^ ((row & 7) << 3);
          a[f] = *(const short8v*)(Pw + off);
          b[f] = *(const short8v*)(Xp + (long)f * 16 * LP + ks * 32);
        }
#pragma unroll
        for (int i = 0; i < 4; ++i)
#pragma unroll
          for (int j = 0; j < 4; ++j)
            yacc[i][j] = __builtin_amdgcn_mfma_f32_16x16x32_bf16(a[i], b[j], yacc[i][j], 0, 0, 0);
      }
    }

    // store y for this head (bf16)
#pragma unroll
    for (int i = 0; i < 4; ++i)
#pragma unroll
      for (int r = 0; r < 4; ++r) {
        int lgl = l0 + i * 16 + lg * 4 + r;
        if ((L % 64 == 0) || lgl < L) {
#pragma unroll
          for (int j = 0; j < 4; ++j)
            y[((long)seq * L + lgl) * 512 + h * 64 + j * 16 + lr] = f2bf(yacc[i][j][r]);
        }
      }
  }
}

// ---------------- gate: ybh = rmsnorm((y + D*xh) * silu(z)) * gn_w  (bf16 out)
__global__ __launch_bounds__(256) void k_gate2(const short* __restrict__ y,
                                               const float* __restrict__ zx,
                                               const short* __restrict__ xbc,
                                               const float* __restrict__ Dp,
                                               const float* __restrict__ gnw,
                                               short* __restrict__ ybh) {
  int m = blockIdx.x * 4 + (threadIdx.x >> 6);
  int lane = threadIdx.x & 63;
  int d0 = lane * 8;
  short8v yv = *(const short8v*)(y + (long)m * 512 + d0);
  short8v xv = *(const short8v*)(xbc + (long)m * 640 + d0);
  float4 za = *(const float4*)(zx + (long)m * PROJP + d0);
  float4 zb = *(const float4*)(zx + (long)m * PROJP + d0 + 4);
  float Dh = Dp[lane >> 3];
  float zf[8] = {za.x, za.y, za.z, za.w, zb.x, zb.y, zb.z, zb.w};
  float g[8];
  float ss = 0.f;
#pragma unroll
  for (int i = 0; i < 8; ++i) {
    float zi = zf[i];
    g[i] = (bf2f(yv[i]) + Dh * bf2f(xv[i])) * zi / (1.f + __expf(-zi));
    ss += g[i] * g[i];
  }
  ss = wave_sum64(ss);
  float scl = rsqrtf(ss * (1.f / 512.f) + 1e-6f);
  short8v o;
#pragma unroll
  for (int i = 0; i < 8; ++i) o[i] = f2bf(g[i] * scl * gnw[d0 + i]);
  *(short8v*)(ybh + (long)m * 512 + d0) = o;
}

extern "C" void kernel_launch(void* const* d_in, const int* in_sizes, int n_in,
                              void* d_out, int out_size, void* d_ws, size_t ws_size,
                              hipStream_t stream) {
  (void)in_sizes; (void)n_in; (void)out_size; (void)ws_size;
  const float* x = (const float*)d_in[0];
  float* out = (float*)d_out;
  const long M = MTOK;

  char* p = (char*)d_ws;
  float* zx = (float*)p;     p += (size_t)M * PROJP * 4;       // 121.9 MB
  short* bufn = (short*)p;   p += (size_t)M * 256 * 2;         // 12.2 MB
  short* xbc = (short*)p;    p += (size_t)M * 640 * 2 + 4096;  // 30.5 MB
  float* dtb = (float*)p;    p += (size_t)M * 8 * 4;
  float* cumb = (float*)p;   p += (size_t)M * 8 * 4;
  short* ybuf = (short*)p;   p += (size_t)M * 512 * 2;         // 24.4 MB
  short* xT = (short*)p;     p += (size_t)12582912 * 2;        // 25.2 MB
  short* ybh = (short*)p;    p += (size_t)M * 512 * 2;         // 24.4 MB
  short* WinT = (short*)p;   p += (size_t)4 * PROJP * 256 * 2; // 2.6 MB
  short* WoutT = (short*)p;  p += (size_t)4 * 256 * 512 * 2;   // 1.0 MB

  // weight prep (every call; deterministic)
  k_wt<<<dim3((PROJP * 256 + 255) / 256, 1, 4), 256, 0, stream>>>(
      (const float*)d_in[2], (const float*)d_in[11], WinT, 256, 1160, PROJP);
  k_wt<<<dim3((256 * 512 + 255) / 256, 1, 4), 256, 0, stream>>>(
      (const float*)d_in[9], (const float*)d_in[18], WoutT, 512, 256, 256);

  hipMemcpyAsync(out, x, (size_t)M * 256 * sizeof(float), hipMemcpyDeviceToDevice, stream);

  for (int layer = 0; layer < 2; ++layer) {
    for (int path = 0; path < 2; ++path) {
      const float* const* P = (const float* const*)(d_in + 1 + path * 9);
      const float* nw = P[0] + layer * 256;
      const float* Wc = P[2] + layer * 640 * 4;
      const float* bc = P[3] + layer * 640;
      const float* dtbias = P[4] + layer * 8;
      const float* Alog = P[5] + layer * 8;
      const float* Dp = P[6] + layer * 8;
      const float* gnw = P[7] + layer * 512;
      const short* WinTp = WinT + (long)(path * 2 + layer) * PROJP * 256;
      const short* WoutTp = WoutT + (long)(path * 2 + layer) * 256 * 512;
      int L = (path == 0) ? 192 : 62;
      int nseq = (path == 0) ? 124 : 384;

      if (path == 0) k_rmsnorm_in<true><<<MTOK / 4, 256, 0, stream>>>(out, nw, bufn);
      else           k_rmsnorm_in<false><<<MTOK / 4, 256, 0, stream>>>(out, nw, bufn);

      gemm_mfma<0><<<dim3(PROJP / 128, MTOK / 128), 256, 0, stream>>>(bufn, WinTp, zx, 256, PROJP);

      k_conv<<<(MTOK * 640 + 255) / 256, 256, 0, stream>>>(zx, Wc, bc, xbc, L);
      k_scan<<<(nseq * 8 + 3) / 4, 256, 0, stream>>>(zx, dtbias, Alog, dtb, cumb, nseq, L);

      if (path == 0) k_xt<192><<<dim3(nseq, 8, 3), 256, 0, stream>>>(xbc, xT);
      else           k_xt<62><<<dim3(nseq, 8, 1), 256, 0, stream>>>(xbc, xT);

      if (path == 0) k_ssd2<192, 3><<<dim3(nseq, 3), 256, 0, stream>>>(xbc, xT, dtb, cumb, Alog, ybuf);
      else           k_ssd2<62, 1><<<dim3(nseq, 1), 256, 0, stream>>>(xbc, xT, dtb, cumb, Alog, ybuf);

      k_gate2<<<MTOK / 4, 256, 0, stream>>>(ybuf, zx, xbc, Dp, gnw, ybh);

      if (path == 0) gemm_mfma<1><<<dim3(2, MTOK / 128), 256, 0, stream>>>(ybh, WoutTp, out, 512, 0);
      else           gemm_mfma<2><<<dim3(2, MTOK / 128), 256, 0, stream>>>(ybh, WoutTp, out, 512, 0);
    }
  }
}

// Round 4
// 1270.867 us; speedup vs baseline: 2.1136x; 1.0023x over previous
//
#include <hip/hip_runtime.h>
#include <hip/hip_bf16.h>

// DualPathModule: 2 layers x (t-path, b-path) Mamba2, bf16-MFMA version.
// HID=256, DIN=512, NHEADS=8, HEADP=64, DSTATE=64, CONVDIM=640, PROJ=1160 (padded 1280)
// t-path: 124 seqs x L=192 (strided in x); b-path: 384 seqs x L=62. M=23808.

#define MTOK   23808
#define PROJP  1280   // padded projection dim (row stride of zx, WinT rows)

typedef __attribute__((ext_vector_type(8))) short short8v;
typedef __attribute__((ext_vector_type(4))) short short4v;
typedef __attribute__((ext_vector_type(4))) float f32x4;

__device__ __forceinline__ float wave_sum64(float v) {
#pragma unroll
  for (int off = 32; off; off >>= 1) v += __shfl_xor(v, off, 64);
  return v;
}

__device__ __forceinline__ short f2bf(float f) {
  union { float f; unsigned u; } v; v.f = f;
  unsigned r = (v.u + 0x7fffu + ((v.u >> 16) & 1u)) >> 16;  // RNE
  return (short)r;
}
__device__ __forceinline__ float bf2f(short s) {
  union { unsigned u; float f; } v; v.u = ((unsigned)(unsigned short)s) << 16; return v.f;
}

// token m of t-path (seq = b*62+nb, time tt) -> flat offset in x (B,T,NB,H)
__device__ __forceinline__ long t_base(int m) {
  int seq = m / 192, tt = m - seq * 192;
  int b = seq / 62, nb = seq - b * 62;
  return ((long)((b * 192 + tt) * 62 + nb)) * 256;
}

// ---------------- weight transpose+cvt: dst[z][n][k] = src_z[k][n], n>=N zero-padded
__global__ __launch_bounds__(256) void k_wt(const float* __restrict__ tW,
                                            const float* __restrict__ bW,
                                            short* __restrict__ dst, int K, int N, int NP) {
  int z = blockIdx.z;
  const float* src = (z >> 1 ? bW : tW) + (long)(z & 1) * K * N;
  short* d = dst + (long)z * NP * K;
  int idx = blockIdx.x * 256 + threadIdx.x;
  if (idx >= NP * K) return;
  int n = idx / K, k = idx - n * K;
  d[idx] = (n < N) ? f2bf(src[(long)k * N + n]) : (short)0;
}

// ---------------- gather + rmsnorm over H=256 -> bufn[M x 256] bf16
template <bool TPATH>
__global__ __launch_bounds__(256) void k_rmsnorm_in(const float* __restrict__ xio,
                                                    const float* __restrict__ w,
                                                    short* __restrict__ outb) {
  int m = blockIdx.x * 4 + (threadIdx.x >> 6);
  int lane = threadIdx.x & 63;
  long base = TPATH ? t_base(m) : (long)m * 256;
  float4 v = *(const float4*)(xio + base + lane * 4);
  float ss = v.x * v.x + v.y * v.y + v.z * v.z + v.w * v.w;
  ss = wave_sum64(ss);
  float sc = rsqrtf(ss * (1.f / 256.f) + 1e-6f);
  float4 wv = *(const float4*)(w + lane * 4);
  short4v o;
  o[0] = f2bf(v.x * sc * wv.x); o[1] = f2bf(v.y * sc * wv.y);
  o[2] = f2bf(v.z * sc * wv.z); o[3] = f2bf(v.w * sc * wv.w);
  *(short4v*)(outb + (long)m * 256 + lane * 4) = o;
}

// ---------------- MFMA GEMM: C[M x N] = A[M x K] * WT[N x K]^T  (bf16 in, f32 acc)
// block 128x128 (4 waves 2x2, each 64x64). EPI: 0 plain f32 store (ldc),
// 1 t-path residual add into out, 2 b-path residual add.
template <int EPI>
__global__ __launch_bounds__(256) void gemm_mfma(const short* __restrict__ A,
                                                 const short* __restrict__ WT,
                                                 float* __restrict__ C,
                                                 int K, int ldc) {
  int w = threadIdx.x >> 6, lane = threadIdx.x & 63;
  int m0 = blockIdx.y * 128 + (w >> 1) * 64;
  int n0 = blockIdx.x * 128 + (w & 1) * 64;
  int lr = lane & 15, lg = lane >> 4;
  f32x4 acc[4][4];
#pragma unroll
  for (int i = 0; i < 4; ++i)
#pragma unroll
    for (int j = 0; j < 4; ++j) acc[i][j] = (f32x4){0.f, 0.f, 0.f, 0.f};
  const short* Ap = A + (long)(m0 + lr) * K + lg * 8;
  const short* Bp = WT + (long)(n0 + lr) * K + lg * 8;
#pragma unroll 2
  for (int k0 = 0; k0 < K; k0 += 32) {
    short8v a[4], b[4];
#pragma unroll
    for (int f = 0; f < 4; ++f) {
      a[f] = *(const short8v*)(Ap + (long)f * 16 * K + k0);
      b[f] = *(const short8v*)(Bp + (long)f * 16 * K + k0);
    }
#pragma unroll
    for (int i = 0; i < 4; ++i)
#pragma unroll
      for (int j = 0; j < 4; ++j)
        acc[i][j] = __builtin_amdgcn_mfma_f32_16x16x32_bf16(a[i], b[j], acc[i][j], 0, 0, 0);
  }
#pragma unroll
  for (int i = 0; i < 4; ++i)
#pragma unroll
    for (int j = 0; j < 4; ++j)
#pragma unroll
      for (int r = 0; r < 4; ++r) {
        int m = m0 + i * 16 + lg * 4 + r;
        int n = n0 + j * 16 + lr;
        if (EPI == 0) {
          C[(long)m * ldc + n] = acc[i][j][r];
        } else {
          long base = (EPI == 1) ? t_base(m) : (long)m * 256;
          C[base + n] += acc[i][j][r];
        }
      }
}

// ---------------- causal depthwise conv(K=4) + silu -> xBC[M x 640] bf16
__global__ __launch_bounds__(256) void k_conv(const float* __restrict__ zx,
                                              const float* __restrict__ Wc,
                                              const float* __restrict__ bc,
                                              short* __restrict__ xBC, int L) {
  int idx = blockIdx.x * 256 + threadIdx.x;
  if (idx >= MTOK * 640) return;
  int m = idx / 640, c = idx - m * 640;
  int tpos = m % L;
  float acc = bc[c];
#pragma unroll
  for (int k = 0; k < 4; ++k) {
    int tt = tpos - 3 + k;
    if (tt >= 0) acc += Wc[c * 4 + k] * zx[(long)(m - 3 + k) * PROJP + 512 + c];
  }
  xBC[(long)m * 640 + c] = f2bf(acc / (1.f + __expf(-acc)));
}

// ---------------- fused softplus(dt) + per-(seq,head) inclusive scan of dt*A
__global__ __launch_bounds__(256) void k_scan(const float* __restrict__ zx,
                                              const float* __restrict__ dtbias,
                                              const float* __restrict__ A_log,
                                              float* __restrict__ dtb,
                                              float* __restrict__ cumb,
                                              int nseq, int L) {
  int wid = blockIdx.x * 4 + (threadIdx.x >> 6);
  if (wid >= nseq * 8) return;
  int seq = wid >> 3, h = wid & 7, lane = threadIdx.x & 63;
  float Ah = -__expf(A_log[h]);
  float bias = dtbias[h];
  float run = 0.f;
  for (int t0 = 0; t0 < L; t0 += 64) {
    int tt = t0 + lane;
    float d = 0.f;
    if (tt < L) {
      float v = zx[((long)seq * L + tt) * PROJP + 1152 + h] + bias;
      d = (v > 20.f) ? v : log1pf(__expf(v));
    }
    float s = d * Ah;
#pragma unroll
    for (int off = 1; off < 64; off <<= 1) {
      float o = __shfl_up(s, off, 64);
      if (lane >= off) s += o;
    }
    if (tt < L) {
      long m = (long)seq * L + tt;
      dtb[m * 8 + h] = d;
      cumb[m * 8 + h] = run + s;
    }
    run += __shfl(s, 63, 64);
  }
}

// ---------------- x transpose: xT[(seq*8+h)*64 + p][LP] = x[s][h*64+p], zero-padded s>=L
template <int L>
__global__ __launch_bounds__(256) void k_xt(const short* __restrict__ xbc,
                                            short* __restrict__ xT) {
  constexpr int LP = (L + 63) & ~63;
  int seq = blockIdx.x, h = blockIdx.y, st = blockIdx.z;
  __shared__ short tile[64][72];
  int t = threadIdx.x;
  for (int e = t; e < 512; e += 256) {
    int s = e >> 3, p8 = (e & 7) * 8;
    int sg = st * 64 + s;
    union { short8v v; short a[8]; } u;
    if (sg < L) u.v = *(const short8v*)(xbc + ((long)seq * L + sg) * 640 + h * 64 + p8);
    else {
#pragma unroll
      for (int j = 0; j < 8; ++j) u.a[j] = 0;
    }
    *(short8v*)&tile[s][p8] = u.v;
  }
  __syncthreads();
  for (int e = t; e < 512; e += 256) {
    int p = e >> 3, s8 = (e & 7) * 8;
    union { short8v v; short a[8]; } u;
#pragma unroll
    for (int j = 0; j < 8; ++j) u.a[j] = tile[s8 + j][p];
    *(short8v*)(xT + ((long)(seq * 8 + h) * 64 + p) * LP + st * 64 + s8) = u.v;
  }
}

// ---------------- SSD via MFMA, occupancy-oriented. Block = (seq, lt, head).
// 4 waves; wave w owns output rows [lt*64 + w*16, +16). No __syncthreads in the
// c-loop: per-wave private swizzled P buffer (2KB) in LDS, cum/dt from global (L2).
// fwd (s<=l): exp(cum_l - cum_s); rev (s>=l): exp(cumP_s - cumP_l); diagonal twice.
template <int L, int NCH>
__global__ __launch_bounds__(256) void k_ssd3(const short* __restrict__ xbc,
                                              const short* __restrict__ xT,
                                              const float* __restrict__ dtb,
                                              const float* __restrict__ cumb,
                                              const float* __restrict__ A_log,
                                              short* __restrict__ y) {
  constexpr int LP = (L + 63) & ~63;
  constexpr bool FULL = (L % 64) == 0;
  int seq = blockIdx.x, lt = blockIdx.y, h = blockIdx.z;
  int w = threadIdx.x >> 6, lane = threadIdx.x & 63;
  int lr = lane & 15, lg = lane >> 4;
  int lw = lt * 64 + w * 16;  // wave's first output row

  __shared__ short sP[4][1024];  // per-wave 16x64 bf16, XOR-swizzled
  short* Pw = sP[w];

  float Ah = -__expf(A_log[h]);

  // l-side cum/dt for lane's 4 rows: l = lw + lg*4 + r
  float cl[4], cpl[4];
#pragma unroll
  for (int r = 0; r < 4; ++r) {
    int lgl = lw + lg * 4 + r;
    int lc = FULL ? lgl : (lgl < L ? lgl : L - 1);
    long m = (long)seq * L + lc;
    float cv = cumb[m * 8 + h], dv = dtb[m * 8 + h];
    cl[r] = cv; cpl[r] = cv - dv * Ah;
  }

  f32x4 yacc[4];
#pragma unroll
  for (int j = 0; j < 4; ++j) yacc[j] = (f32x4){0.f, 0.f, 0.f, 0.f};

  // A-operand rows for phase A: C rows lw + lr (clamped for tail)
  int crow = FULL ? (lw + lr) : (lw + lr < L ? lw + lr : L - 1);
  const short* Cp = xbc + ((long)seq * L + crow) * 640 + 576 + lg * 8;

  for (int c = 0; c < NCH; ++c) {
    int c64 = c * 64;
    // s-side cum/dt for lane's 4 columns: s = c64 + j*16 + lr
    float cs[4], cps[4], ds[4];
#pragma unroll
    for (int j = 0; j < 4; ++j) {
      int sgl = c64 + j * 16 + lr;
      int sc_ = FULL ? sgl : (sgl < L ? sgl : L - 1);
      long m = (long)seq * L + sc_;
      float cv = cumb[m * 8 + h], dv = dtb[m * 8 + h];
      cs[j] = cv; cps[j] = cv - dv * Ah; ds[j] = dv;
    }

    // ---- phase A: CB rows = C_rows . B^T  (k = dstate 64, 2 k-steps)
    f32x4 cb[4];
#pragma unroll
    for (int j = 0; j < 4; ++j) cb[j] = (f32x4){0.f, 0.f, 0.f, 0.f};
#pragma unroll
    for (int ks = 0; ks < 2; ++ks) {
      short8v a = *(const short8v*)(Cp + ks * 32);
      short8v b[4];
#pragma unroll
      for (int j = 0; j < 4; ++j) {
        int srow = c64 + j * 16 + lr;
        if (!FULL) srow = srow < L ? srow : L - 1;
        b[j] = *(const short8v*)(xbc + ((long)seq * L + srow) * 640 + 512 + lg * 8 + ks * 32);
      }
#pragma unroll
      for (int j = 0; j < 4; ++j)
        cb[j] = __builtin_amdgcn_mfma_f32_16x16x32_bf16(a, b[j], cb[j], 0, 0, 0);
    }

    // ---- decay weighting -> P (bf16) into wave-private swizzled LDS
#pragma unroll
    for (int j = 0; j < 4; ++j) {
      int sgl = c64 + j * 16 + lr;
#pragma unroll
      for (int r = 0; r < 4; ++r) {
        int lrow = lg * 4 + r;
        int lgl = lw + lrow;
        float wgt = 0.f;
        if (FULL || (lgl < L && sgl < L)) {
          if (sgl <= lgl) wgt += __expf(cl[r] - cs[j]);
          if (sgl >= lgl) wgt += __expf(cps[j] - cpl[r]);
        }
        float p = cb[j][r] * wgt * ds[j];
        Pw[(lrow * 64 + j * 16 + lr) ^ ((lrow & 7) << 3)] = f2bf(p);
      }
    }

    // ---- phase B: yacc += P . X_h  (k = s 64, 2 k-steps)
#pragma unroll
    for (int ks = 0; ks < 2; ++ks) {
      short8v a = *(const short8v*)(Pw + ((lr * 64 + ks * 32 + lg * 8) ^ ((lr & 7) << 3)));
      short8v b[4];
#pragma unroll
      for (int j = 0; j < 4; ++j)
        b[j] = *(const short8v*)(xT + ((long)(seq * 8 + h) * 64 + j * 16 + lr) * LP +
                                 c64 + ks * 32 + lg * 8);
#pragma unroll
      for (int j = 0; j < 4; ++j)
        yacc[j] = __builtin_amdgcn_mfma_f32_16x16x32_bf16(a, b[j], yacc[j], 0, 0, 0);
    }
  }

  // store y (bf16): rows lw + lg*4 + r, cols h*64 + j*16 + lr
#pragma unroll
  for (int r = 0; r < 4; ++r) {
    int lgl = lw + lg * 4 + r;
    if (FULL || lgl < L) {
      short* yp = y + ((long)seq * L + lgl) * 512 + h * 64 + lr;
#pragma unroll
      for (int j = 0; j < 4; ++j) yp[j * 16] = f2bf(yacc[j][r]);
    }
  }
}

// ---------------- gate: ybh = rmsnorm((y + D*xh) * silu(z)) * gn_w  (bf16 out)
__global__ __launch_bounds__(256) void k_gate2(const short* __restrict__ y,
                                               const float* __restrict__ zx,
                                               const short* __restrict__ xbc,
                                               const float* __restrict__ Dp,
                                               const float* __restrict__ gnw,
                                               short* __restrict__ ybh) {
  int m = blockIdx.x * 4 + (threadIdx.x >> 6);
  int lane = threadIdx.x & 63;
  int d0 = lane * 8;
  short8v yv = *(const short8v*)(y + (long)m * 512 + d0);
  short8v xv = *(const short8v*)(xbc + (long)m * 640 + d0);
  float4 za = *(const float4*)(zx + (long)m * PROJP + d0);
  float4 zb = *(const float4*)(zx + (long)m * PROJP + d0 + 4);
  float Dh = Dp[lane >> 3];
  float zf[8] = {za.x, za.y, za.z, za.w, zb.x, zb.y, zb.z, zb.w};
  float g[8];
  float ss = 0.f;
#pragma unroll
  for (int i = 0; i < 8; ++i) {
    float zi = zf[i];
    g[i] = (bf2f(yv[i]) + Dh * bf2f(xv[i])) * zi / (1.f + __expf(-zi));
    ss += g[i] * g[i];
  }
  ss = wave_sum64(ss);
  float scl = rsqrtf(ss * (1.f / 512.f) + 1e-6f);
  short8v o;
#pragma unroll
  for (int i = 0; i < 8; ++i) o[i] = f2bf(g[i] * scl * gnw[d0 + i]);
  *(short8v*)(ybh + (long)m * 512 + d0) = o;
}

extern "C" void kernel_launch(void* const* d_in, const int* in_sizes, int n_in,
                              void* d_out, int out_size, void* d_ws, size_t ws_size,
                              hipStream_t stream) {
  (void)in_sizes; (void)n_in; (void)out_size; (void)ws_size;
  const float* x = (const float*)d_in[0];
  float* out = (float*)d_out;
  const long M = MTOK;

  char* p = (char*)d_ws;
  float* zx = (float*)p;     p += (size_t)M * PROJP * 4;       // 121.9 MB
  short* bufn = (short*)p;   p += (size_t)M * 256 * 2;         // 12.2 MB
  short* xbc = (short*)p;    p += (size_t)M * 640 * 2 + 4096;  // 30.5 MB
  float* dtb = (float*)p;    p += (size_t)M * 8 * 4;
  float* cumb = (float*)p;   p += (size_t)M * 8 * 4;
  short* ybuf = (short*)p;   p += (size_t)M * 512 * 2;         // 24.4 MB
  short* xT = (short*)p;     p += (size_t)12582912 * 2;        // 25.2 MB
  short* ybh = (short*)p;    p += (size_t)M * 512 * 2;         // 24.4 MB
  short* WinT = (short*)p;   p += (size_t)4 * PROJP * 256 * 2; // 2.6 MB
  short* WoutT = (short*)p;  p += (size_t)4 * 256 * 512 * 2;   // 1.0 MB

  // weight prep (every call; deterministic)
  k_wt<<<dim3((PROJP * 256 + 255) / 256, 1, 4), 256, 0, stream>>>(
      (const float*)d_in[2], (const float*)d_in[11], WinT, 256, 1160, PROJP);
  k_wt<<<dim3((256 * 512 + 255) / 256, 1, 4), 256, 0, stream>>>(
      (const float*)d_in[9], (const float*)d_in[18], WoutT, 512, 256, 256);

  hipMemcpyAsync(out, x, (size_t)M * 256 * sizeof(float), hipMemcpyDeviceToDevice, stream);

  for (int layer = 0; layer < 2; ++layer) {
    for (int path = 0; path < 2; ++path) {
      const float* const* P = (const float* const*)(d_in + 1 + path * 9);
      const float* nw = P[0] + layer * 256;
      const float* Wc = P[2] + layer * 640 * 4;
      const float* bc = P[3] + layer * 640;
      const float* dtbias = P[4] + layer * 8;
      const float* Alog = P[5] + layer * 8;
      const float* Dp = P[6] + layer * 8;
      const float* gnw = P[7] + layer * 512;
      const short* WinTp = WinT + (long)(path * 2 + layer) * PROJP * 256;
      const short* WoutTp = WoutT + (long)(path * 2 + layer) * 256 * 512;
      int L = (path == 0) ? 192 : 62;
      int nseq = (path == 0) ? 124 : 384;

      if (path == 0) k_rmsnorm_in<true><<<MTOK / 4, 256, 0, stream>>>(out, nw, bufn);
      else           k_rmsnorm_in<false><<<MTOK / 4, 256, 0, stream>>>(out, nw, bufn);

      gemm_mfma<0><<<dim3(PROJP / 128, MTOK / 128), 256, 0, stream>>>(bufn, WinTp, zx, 256, PROJP);

      k_conv<<<(MTOK * 640 + 255) / 256, 256, 0, stream>>>(zx, Wc, bc, xbc, L);
      k_scan<<<(nseq * 8 + 3) / 4, 256, 0, stream>>>(zx, dtbias, Alog, dtb, cumb, nseq, L);

      if (path == 0) k_xt<192><<<dim3(nseq, 8, 3), 256, 0, stream>>>(xbc, xT);
      else           k_xt<62><<<dim3(nseq, 8, 1), 256, 0, stream>>>(xbc, xT);

      if (path == 0) k_ssd3<192, 3><<<dim3(nseq, 3, 8), 256, 0, stream>>>(xbc, xT, dtb, cumb, Alog, ybuf);
      else           k_ssd3<62, 1><<<dim3(nseq, 1, 8), 256, 0, stream>>>(xbc, xT, dtb, cumb, Alog, ybuf);

      k_gate2<<<MTOK / 4, 256, 0, stream>>>(ybuf, zx, xbc, Dp, gnw, ybh);

      if (path == 0) gemm_mfma<1><<<dim3(2, MTOK / 128), 256, 0, stream>>>(ybh, WoutTp, out, 512, 0);
      else           gemm_mfma<2><<<dim3(2, MTOK / 128), 256, 0, stream>>>(ybh, WoutTp, out, 512, 0);
    }
  }
}

// Round 5
// 1135.078 us; speedup vs baseline: 2.3665x; 1.1196x over previous
//
#include <hip/hip_runtime.h>
#include <hip/hip_bf16.h>

// DualPathModule: 2 layers x (t-path, b-path) Mamba2, bf16-MFMA version.
// HID=256, DIN=512, NHEADS=8, HEADP=64, DSTATE=64, CONVDIM=640, PROJ=1160 (padded 1280)
// t-path: 124 seqs x L=192 (strided in x); b-path: 384 seqs x L=62. M=23808.

#define MTOK   23808
#define PROJP  1280   // padded projection dim (row stride of zx, WinT rows)

typedef __attribute__((ext_vector_type(8))) short short8v;
typedef __attribute__((ext_vector_type(4))) short short4v;
typedef __attribute__((ext_vector_type(4))) float f32x4;

__device__ __forceinline__ float wave_sum64(float v) {
#pragma unroll
  for (int off = 32; off; off >>= 1) v += __shfl_xor(v, off, 64);
  return v;
}

__device__ __forceinline__ short f2bf(float f) {
  union { float f; unsigned u; } v; v.f = f;
  unsigned r = (v.u + 0x7fffu + ((v.u >> 16) & 1u)) >> 16;  // RNE
  return (short)r;
}
__device__ __forceinline__ float bf2f(short s) {
  union { unsigned u; float f; } v; v.u = ((unsigned)(unsigned short)s) << 16; return v.f;
}

// token m of t-path (seq = b*62+nb, time tt) -> flat offset in x (B,T,NB,H)
__device__ __forceinline__ long t_base(int m) {
  int seq = m / 192, tt = m - seq * 192;
  int b = seq / 62, nb = seq - b * 62;
  return ((long)((b * 192 + tt) * 62 + nb)) * 256;
}

// ---------------- weight transpose+cvt: dst[z][n][k] = src_z[k][n], n>=N zero-padded
__global__ __launch_bounds__(256) void k_wt(const float* __restrict__ tW,
                                            const float* __restrict__ bW,
                                            short* __restrict__ dst, int K, int N, int NP) {
  int z = blockIdx.z;
  const float* src = (z >> 1 ? bW : tW) + (long)(z & 1) * K * N;
  short* d = dst + (long)z * NP * K;
  int idx = blockIdx.x * 256 + threadIdx.x;
  if (idx >= NP * K) return;
  int n = idx / K, k = idx - n * K;
  d[idx] = (n < N) ? f2bf(src[(long)k * N + n]) : (short)0;
}

// ---------------- gather + rmsnorm over H=256 -> bufn[M x 256] bf16
template <bool TPATH>
__global__ __launch_bounds__(256) void k_rmsnorm_in(const float* __restrict__ xio,
                                                    const float* __restrict__ w,
                                                    short* __restrict__ outb) {
  int m = blockIdx.x * 4 + (threadIdx.x >> 6);
  int lane = threadIdx.x & 63;
  long base = TPATH ? t_base(m) : (long)m * 256;
  float4 v = *(const float4*)(xio + base + lane * 4);
  float ss = v.x * v.x + v.y * v.y + v.z * v.z + v.w * v.w;
  ss = wave_sum64(ss);
  float sc = rsqrtf(ss * (1.f / 256.f) + 1e-6f);
  float4 wv = *(const float4*)(w + lane * 4);
  short4v o;
  o[0] = f2bf(v.x * sc * wv.x); o[1] = f2bf(v.y * sc * wv.y);
  o[2] = f2bf(v.z * sc * wv.z); o[3] = f2bf(v.w * sc * wv.w);
  *(short4v*)(outb + (long)m * 256 + lane * 4) = o;
}

// ---------------- MFMA GEMM: C[M x N] = A[M x K] * WT[N x K]^T  (bf16 in, f32 acc)
// block 128x128 (4 waves 2x2, each 64x64). EPI: 0 plain f32 store (ldc),
// 1 t-path residual add into out, 2 b-path residual add.
template <int EPI>
__global__ __launch_bounds__(256) void gemm_mfma(const short* __restrict__ A,
                                                 const short* __restrict__ WT,
                                                 float* __restrict__ C,
                                                 int K, int ldc) {
  int w = threadIdx.x >> 6, lane = threadIdx.x & 63;
  int m0 = blockIdx.y * 128 + (w >> 1) * 64;
  int n0 = blockIdx.x * 128 + (w & 1) * 64;
  int lr = lane & 15, lg = lane >> 4;
  f32x4 acc[4][4];
#pragma unroll
  for (int i = 0; i < 4; ++i)
#pragma unroll
    for (int j = 0; j < 4; ++j) acc[i][j] = (f32x4){0.f, 0.f, 0.f, 0.f};
  const short* Ap = A + (long)(m0 + lr) * K + lg * 8;
  const short* Bp = WT + (long)(n0 + lr) * K + lg * 8;
#pragma unroll 2
  for (int k0 = 0; k0 < K; k0 += 32) {
    short8v a[4], b[4];
#pragma unroll
    for (int f = 0; f < 4; ++f) {
      a[f] = *(const short8v*)(Ap + (long)f * 16 * K + k0);
      b[f] = *(const short8v*)(Bp + (long)f * 16 * K + k0);
    }
#pragma unroll
    for (int i = 0; i < 4; ++i)
#pragma unroll
      for (int j = 0; j < 4; ++j)
        acc[i][j] = __builtin_amdgcn_mfma_f32_16x16x32_bf16(a[i], b[j], acc[i][j], 0, 0, 0);
  }
#pragma unroll
  for (int i = 0; i < 4; ++i)
#pragma unroll
    for (int j = 0; j < 4; ++j)
#pragma unroll
      for (int r = 0; r < 4; ++r) {
        int m = m0 + i * 16 + lg * 4 + r;
        int n = n0 + j * 16 + lr;
        if (EPI == 0) {
          C[(long)m * ldc + n] = acc[i][j][r];
        } else {
          long base = (EPI == 1) ? t_base(m) : (long)m * 256;
          C[base + n] += acc[i][j][r];
        }
      }
}

// ---------------- causal depthwise conv(K=4) + silu -> xBC[M x 640] bf16
__global__ __launch_bounds__(256) void k_conv(const float* __restrict__ zx,
                                              const float* __restrict__ Wc,
                                              const float* __restrict__ bc,
                                              short* __restrict__ xBC, int L) {
  int idx = blockIdx.x * 256 + threadIdx.x;
  if (idx >= MTOK * 640) return;
  int m = idx / 640, c = idx - m * 640;
  int tpos = m % L;
  float acc = bc[c];
#pragma unroll
  for (int k = 0; k < 4; ++k) {
    int tt = tpos - 3 + k;
    if (tt >= 0) acc += Wc[c * 4 + k] * zx[(long)(m - 3 + k) * PROJP + 512 + c];
  }
  xBC[(long)m * 640 + c] = f2bf(acc / (1.f + __expf(-acc)));
}

// ---------------- fused softplus(dt) + per-(seq,head) inclusive scan of dt*A
__global__ __launch_bounds__(256) void k_scan(const float* __restrict__ zx,
                                              const float* __restrict__ dtbias,
                                              const float* __restrict__ A_log,
                                              float* __restrict__ dtb,
                                              float* __restrict__ cumb,
                                              int nseq, int L) {
  int wid = blockIdx.x * 4 + (threadIdx.x >> 6);
  if (wid >= nseq * 8) return;
  int seq = wid >> 3, h = wid & 7, lane = threadIdx.x & 63;
  float Ah = -__expf(A_log[h]);
  float bias = dtbias[h];
  float run = 0.f;
  for (int t0 = 0; t0 < L; t0 += 64) {
    int tt = t0 + lane;
    float d = 0.f;
    if (tt < L) {
      float v = zx[((long)seq * L + tt) * PROJP + 1152 + h] + bias;
      d = (v > 20.f) ? v : log1pf(__expf(v));
    }
    float s = d * Ah;
#pragma unroll
    for (int off = 1; off < 64; off <<= 1) {
      float o = __shfl_up(s, off, 64);
      if (lane >= off) s += o;
    }
    if (tt < L) {
      long m = (long)seq * L + tt;
      dtb[m * 8 + h] = d;
      cumb[m * 8 + h] = run + s;
    }
    run += __shfl(s, 63, 64);
  }
}

// ---------------- x transpose: xT[(seq*8+h)*64 + p][LP] = x[s][h*64+p], zero-padded s>=L
template <int L>
__global__ __launch_bounds__(256) void k_xt(const short* __restrict__ xbc,
                                            short* __restrict__ xT) {
  constexpr int LP = (L + 63) & ~63;
  int seq = blockIdx.x, h = blockIdx.y, st = blockIdx.z;
  __shared__ short tile[64][72];
  int t = threadIdx.x;
  for (int e = t; e < 512; e += 256) {
    int s = e >> 3, p8 = (e & 7) * 8;
    int sg = st * 64 + s;
    union { short8v v; short a[8]; } u;
    if (sg < L) u.v = *(const short8v*)(xbc + ((long)seq * L + sg) * 640 + h * 64 + p8);
    else {
#pragma unroll
      for (int j = 0; j < 8; ++j) u.a[j] = 0;
    }
    *(short8v*)&tile[s][p8] = u.v;
  }
  __syncthreads();
  for (int e = t; e < 512; e += 256) {
    int p = e >> 3, s8 = (e & 7) * 8;
    union { short8v v; short a[8]; } u;
#pragma unroll
    for (int j = 0; j < 8; ++j) u.a[j] = tile[s8 + j][p];
    *(short8v*)(xT + ((long)(seq * 8 + h) * 64 + p) * LP + st * 64 + s8) = u.v;
  }
}

// ---------------- SSD v4: shared-CB, in-register P.
// Block = (hg, lt, seq), 4 waves. Phase A: waves cooperatively compute
// CB[64x64] = C_tile . B_chunk^T once (wave w does rows w*16..), store f32 to
// swizzled LDS. Phase B: wave w = head hg*4+w reads CB back in A-fragment
// layout, applies decay in registers (fwd s<=l: exp(cum_l-cum_s); rev s>=l:
// exp(cumP_s-cumP_l); diagonal twice), MFMAs against prefetched xT fragments.
template <int L, int NCH>
__global__ __launch_bounds__(256) void k_ssd4(const short* __restrict__ xbc,
                                              const short* __restrict__ xT,
                                              const float* __restrict__ dtb,
                                              const float* __restrict__ cumb,
                                              const float* __restrict__ A_log,
                                              short* __restrict__ y) {
  constexpr int LP = (L + 63) & ~63;
  constexpr bool FULL = (L % 64) == 0;
  int hg = blockIdx.x, lt = blockIdx.y, seq = blockIdx.z;
  int tid = threadIdx.x, w = tid >> 6, lane = tid & 63;
  int lr = lane & 15, lg = lane >> 4;
  int h = hg * 4 + w;
  int l0 = lt * 64;

  __shared__ float s_cb[64 * 64];     // [l][s ^ ((l&7)<<2)] f32, 16KB
  __shared__ float s_cums[64][8];     // cum for s-chunk, all heads
  __shared__ float s_dts[64][8];      // dt  for s-chunk, all heads

  float Ah = -__expf(A_log[h]);

  // l-side cum/dt for this wave's a-frag rows: l = l0 + i*16 + lr
  float cl[4], cpl[4];
#pragma unroll
  for (int i = 0; i < 4; ++i) {
    int lgl = l0 + i * 16 + lr;
    int lc = FULL ? lgl : (lgl < L ? lgl : L - 1);
    long m = (long)seq * L + lc;
    float cv = cumb[m * 8 + h];
    cl[i] = cv; cpl[i] = cv - dtb[m * 8 + h] * Ah;
  }

  f32x4 yacc[4][4];
#pragma unroll
  for (int i = 0; i < 4; ++i)
#pragma unroll
    for (int j = 0; j < 4; ++j) yacc[i][j] = (f32x4){0.f, 0.f, 0.f, 0.f};

  // phase-A A-operand rows: C rows l0 + w*16 + lr (clamped)
  int crow = l0 + w * 16 + lr;
  if (!FULL) crow = crow < L ? crow : L - 1;
  const short* Cp = xbc + ((long)seq * L + crow) * 640 + 576 + lg * 8;

  for (int c = 0; c < NCH; ++c) {
    int c64 = c * 64;

    // ---- stage s-side cum/dt (waves 0,1)
    if (tid < 128) {
      int r = tid & 63;
      int sg = c64 + r;
      int sc = FULL ? sg : (sg < L ? sg : L - 1);
      const float* src = (tid < 64 ? cumb : dtb) + ((long)seq * L + sc) * 8;
      float4 v0 = *(const float4*)(src);
      float4 v1 = *(const float4*)(src + 4);
      float* dstp = (tid < 64 ? &s_cums[r][0] : &s_dts[r][0]);
      *(float4*)dstp = v0;
      *(float4*)(dstp + 4) = v1;
    }

    // ---- phase A: CB rows [w*16, w*16+16) = C_rows . B_chunk^T
    f32x4 cb4[4];
#pragma unroll
    for (int j = 0; j < 4; ++j) cb4[j] = (f32x4){0.f, 0.f, 0.f, 0.f};
#pragma unroll
    for (int ks = 0; ks < 2; ++ks) {
      short8v a = *(const short8v*)(Cp + ks * 32);
#pragma unroll
      for (int j = 0; j < 4; ++j) {
        int srow = c64 + j * 16 + lr;
        if (!FULL) srow = srow < L ? srow : L - 1;
        short8v b = *(const short8v*)(xbc + ((long)seq * L + srow) * 640 + 512 + lg * 8 + ks * 32);
        cb4[j] = __builtin_amdgcn_mfma_f32_16x16x32_bf16(a, b, cb4[j], 0, 0, 0);
      }
    }
#pragma unroll
    for (int j = 0; j < 4; ++j)
#pragma unroll
      for (int r = 0; r < 4; ++r) {
        int lloc = w * 16 + lg * 4 + r;
        int sloc = j * 16 + lr;
        s_cb[lloc * 64 + (sloc ^ ((lloc & 7) << 2))] = cb4[j][r];
      }

    // ---- prefetch xT fragments for both k-steps (independent of LDS)
    short8v bx[2][4];
#pragma unroll
    for (int ks = 0; ks < 2; ++ks)
#pragma unroll
      for (int j = 0; j < 4; ++j)
        bx[ks][j] = *(const short8v*)(xT + ((long)(seq * 8 + h) * 64 + j * 16 + lr) * LP +
                                      c64 + ks * 32 + lg * 8);

    __syncthreads();  // CB + cum/dt staged

    // ---- phase B: decay in registers -> a-frag, MFMA with xT
#pragma unroll
    for (int ks = 0; ks < 2; ++ks) {
      int sbase = ks * 32 + lg * 8;
      float cs[8], cps[8], dss[8];
#pragma unroll
      for (int e = 0; e < 8; ++e) {
        int sl = sbase + e;
        float cv = s_cums[sl][h];
        float dv = s_dts[sl][h];
        cs[e] = cv; cps[e] = cv - dv * Ah; dss[e] = dv;
      }
#pragma unroll
      for (int i = 0; i < 4; ++i) {
        int R = i * 16 + lr;
        int lgl = l0 + R;
        int sw = (R & 7) << 2;
        int c0 = sbase ^ sw;
        const float* cbrow = &s_cb[R * 64];
        f32x4 lo = *(const f32x4*)(cbrow + c0);
        f32x4 hi = *(const f32x4*)(cbrow + (c0 ^ 4));
        short8v a;
#pragma unroll
        for (int e = 0; e < 8; ++e) {
          int sgl = c64 + sbase + e;
          float cbv = (e < 4) ? lo[e & 3] : hi[e & 3];
          float wgt = 0.f;
          if (sgl <= lgl) wgt += __expf(cl[i] - cs[e]);
          if (sgl >= lgl) wgt += __expf(cps[e] - cpl[i]);
          if (!FULL && (lgl >= L || sgl >= L)) wgt = 0.f;
          a[e] = f2bf(cbv * wgt * dss[e]);
        }
#pragma unroll
        for (int j = 0; j < 4; ++j)
          yacc[i][j] = __builtin_amdgcn_mfma_f32_16x16x32_bf16(a, bx[ks][j], yacc[i][j], 0, 0, 0);
      }
    }
    if (c + 1 < NCH) __syncthreads();  // done reading s_cb before overwrite
  }

  // store y (bf16): rows l0 + i*16 + lg*4 + r, cols h*64 + j*16 + lr
#pragma unroll
  for (int i = 0; i < 4; ++i)
#pragma unroll
    for (int r = 0; r < 4; ++r) {
      int lgl = l0 + i * 16 + lg * 4 + r;
      if (FULL || lgl < L) {
        short* yp = y + ((long)seq * L + lgl) * 512 + h * 64 + lr;
#pragma unroll
        for (int j = 0; j < 4; ++j) yp[j * 16] = f2bf(yacc[i][j][r]);
      }
    }
}

// ---------------- gate: ybh = rmsnorm((y + D*xh) * silu(z)) * gn_w  (bf16 out)
__global__ __launch_bounds__(256) void k_gate2(const short* __restrict__ y,
                                               const float* __restrict__ zx,
                                               const short* __restrict__ xbc,
                                               const float* __restrict__ Dp,
                                               const float* __restrict__ gnw,
                                               short* __restrict__ ybh) {
  int m = blockIdx.x * 4 + (threadIdx.x >> 6);
  int lane = threadIdx.x & 63;
  int d0 = lane * 8;
  short8v yv = *(const short8v*)(y + (long)m * 512 + d0);
  short8v xv = *(const short8v*)(xbc + (long)m * 640 + d0);
  float4 za = *(const float4*)(zx + (long)m * PROJP + d0);
  float4 zb = *(const float4*)(zx + (long)m * PROJP + d0 + 4);
  float Dh = Dp[lane >> 3];
  float zf[8] = {za.x, za.y, za.z, za.w, zb.x, zb.y, zb.z, zb.w};
  float g[8];
  float ss = 0.f;
#pragma unroll
  for (int i = 0; i < 8; ++i) {
    float zi = zf[i];
    g[i] = (bf2f(yv[i]) + Dh * bf2f(xv[i])) * zi / (1.f + __expf(-zi));
    ss += g[i] * g[i];
  }
  ss = wave_sum64(ss);
  float scl = rsqrtf(ss * (1.f / 512.f) + 1e-6f);
  short8v o;
#pragma unroll
  for (int i = 0; i < 8; ++i) o[i] = f2bf(g[i] * scl * gnw[d0 + i]);
  *(short8v*)(ybh + (long)m * 512 + d0) = o;
}

extern "C" void kernel_launch(void* const* d_in, const int* in_sizes, int n_in,
                              void* d_out, int out_size, void* d_ws, size_t ws_size,
                              hipStream_t stream) {
  (void)in_sizes; (void)n_in; (void)out_size; (void)ws_size;
  const float* x = (const float*)d_in[0];
  float* out = (float*)d_out;
  const long M = MTOK;

  char* p = (char*)d_ws;
  float* zx = (float*)p;     p += (size_t)M * PROJP * 4;       // 121.9 MB
  short* bufn = (short*)p;   p += (size_t)M * 256 * 2;         // 12.2 MB
  short* xbc = (short*)p;    p += (size_t)M * 640 * 2 + 4096;  // 30.5 MB
  float* dtb = (float*)p;    p += (size_t)M * 8 * 4;
  float* cumb = (float*)p;   p += (size_t)M * 8 * 4;
  short* ybuf = (short*)p;   p += (size_t)M * 512 * 2;         // 24.4 MB
  short* xT = (short*)p;     p += (size_t)12582912 * 2;        // 25.2 MB
  short* ybh = (short*)p;    p += (size_t)M * 512 * 2;         // 24.4 MB
  short* WinT = (short*)p;   p += (size_t)4 * PROJP * 256 * 2; // 2.6 MB
  short* WoutT = (short*)p;  p += (size_t)4 * 256 * 512 * 2;   // 1.0 MB

  // weight prep (every call; deterministic)
  k_wt<<<dim3((PROJP * 256 + 255) / 256, 1, 4), 256, 0, stream>>>(
      (const float*)d_in[2], (const float*)d_in[11], WinT, 256, 1160, PROJP);
  k_wt<<<dim3((256 * 512 + 255) / 256, 1, 4), 256, 0, stream>>>(
      (const float*)d_in[9], (const float*)d_in[18], WoutT, 512, 256, 256);

  hipMemcpyAsync(out, x, (size_t)M * 256 * sizeof(float), hipMemcpyDeviceToDevice, stream);

  for (int layer = 0; layer < 2; ++layer) {
    for (int path = 0; path < 2; ++path) {
      const float* const* P = (const float* const*)(d_in + 1 + path * 9);
      const float* nw = P[0] + layer * 256;
      const float* Wc = P[2] + layer * 640 * 4;
      const float* bc = P[3] + layer * 640;
      const float* dtbias = P[4] + layer * 8;
      const float* Alog = P[5] + layer * 8;
      const float* Dp = P[6] + layer * 8;
      const float* gnw = P[7] + layer * 512;
      const short* WinTp = WinT + (long)(path * 2 + layer) * PROJP * 256;
      const short* WoutTp = WoutT + (long)(path * 2 + layer) * 256 * 512;
      int L = (path == 0) ? 192 : 62;
      int nseq = (path == 0) ? 124 : 384;

      if (path == 0) k_rmsnorm_in<true><<<MTOK / 4, 256, 0, stream>>>(out, nw, bufn);
      else           k_rmsnorm_in<false><<<MTOK / 4, 256, 0, stream>>>(out, nw, bufn);

      gemm_mfma<0><<<dim3(PROJP / 128, MTOK / 128), 256, 0, stream>>>(bufn, WinTp, zx, 256, PROJP);

      k_conv<<<(MTOK * 640 + 255) / 256, 256, 0, stream>>>(zx, Wc, bc, xbc, L);
      k_scan<<<(nseq * 8 + 3) / 4, 256, 0, stream>>>(zx, dtbias, Alog, dtb, cumb, nseq, L);

      if (path == 0) k_xt<192><<<dim3(nseq, 8, 3), 256, 0, stream>>>(xbc, xT);
      else           k_xt<62><<<dim3(nseq, 8, 1), 256, 0, stream>>>(xbc, xT);

      if (path == 0) k_ssd4<192, 3><<<dim3(2, 3, nseq), 256, 0, stream>>>(xbc, xT, dtb, cumb, Alog, ybuf);
      else           k_ssd4<62, 1><<<dim3(2, 1, nseq), 256, 0, stream>>>(xbc, xT, dtb, cumb, Alog, ybuf);

      k_gate2<<<MTOK / 4, 256, 0, stream>>>(ybuf, zx, xbc, Dp, gnw, ybh);

      if (path == 0) gemm_mfma<1><<<dim3(2, MTOK / 128), 256, 0, stream>>>(ybh, WoutTp, out, 512, 0);
      else           gemm_mfma<2><<<dim3(2, MTOK / 128), 256, 0, stream>>>(ybh, WoutTp, out, 512, 0);
    }
  }
}

// Round 6
// 1056.366 us; speedup vs baseline: 2.5428x; 1.0745x over previous
//
#include <hip/hip_runtime.h>
#include <hip/hip_bf16.h>

// DualPathModule: 2 layers x (t-path, b-path) Mamba2, bf16-MFMA version.
// HID=256, DIN=512, NHEADS=8, HEADP=64, DSTATE=64, CONVDIM=640, PROJ=1160 (padded 1280)
// t-path: 124 seqs x L=192 (strided in x); b-path: 384 seqs x L=62. M=23808.

#define MTOK   23808
#define PROJP  1280   // padded projection dim (row stride of zx, WinT rows)

typedef __attribute__((ext_vector_type(8))) short short8v;
typedef __attribute__((ext_vector_type(4))) short short4v;
typedef __attribute__((ext_vector_type(4))) float f32x4;

__device__ __forceinline__ float wave_sum64(float v) {
#pragma unroll
  for (int off = 32; off; off >>= 1) v += __shfl_xor(v, off, 64);
  return v;
}

__device__ __forceinline__ short f2bf(float f) {
  union { float f; unsigned u; } v; v.f = f;
  unsigned r = (v.u + 0x7fffu + ((v.u >> 16) & 1u)) >> 16;  // RNE
  return (short)r;
}
__device__ __forceinline__ float bf2f(short s) {
  union { unsigned u; float f; } v; v.u = ((unsigned)(unsigned short)s) << 16; return v.f;
}

// token m of t-path (seq = b*62+nb, time tt) -> flat offset in x (B,T,NB,H)
__device__ __forceinline__ long t_base(int m) {
  int seq = m / 192, tt = m - seq * 192;
  int b = seq / 62, nb = seq - b * 62;
  return ((long)((b * 192 + tt) * 62 + nb)) * 256;
}

// ---------------- weight transpose+cvt: dst[z][n][k] = src_z[k][n], n>=N zero-padded
__global__ __launch_bounds__(256) void k_wt(const float* __restrict__ tW,
                                            const float* __restrict__ bW,
                                            short* __restrict__ dst, int K, int N, int NP) {
  int z = blockIdx.z;
  const float* src = (z >> 1 ? bW : tW) + (long)(z & 1) * K * N;
  short* d = dst + (long)z * NP * K;
  int idx = blockIdx.x * 256 + threadIdx.x;
  if (idx >= NP * K) return;
  int n = idx / K, k = idx - n * K;
  d[idx] = (n < N) ? f2bf(src[(long)k * N + n]) : (short)0;
}

// ---------------- gather + rmsnorm over H=256 -> bufn[M x 256] bf16
template <bool TPATH>
__global__ __launch_bounds__(256) void k_rmsnorm_in(const float* __restrict__ xio,
                                                    const float* __restrict__ w,
                                                    short* __restrict__ outb) {
  int m = blockIdx.x * 4 + (threadIdx.x >> 6);
  int lane = threadIdx.x & 63;
  long base = TPATH ? t_base(m) : (long)m * 256;
  float4 v = *(const float4*)(xio + base + lane * 4);
  float ss = v.x * v.x + v.y * v.y + v.z * v.z + v.w * v.w;
  ss = wave_sum64(ss);
  float sc = rsqrtf(ss * (1.f / 256.f) + 1e-6f);
  float4 wv = *(const float4*)(w + lane * 4);
  short4v o;
  o[0] = f2bf(v.x * sc * wv.x); o[1] = f2bf(v.y * sc * wv.y);
  o[2] = f2bf(v.z * sc * wv.z); o[3] = f2bf(v.w * sc * wv.w);
  *(short4v*)(outb + (long)m * 256 + lane * 4) = o;
}

// ---------------- MFMA GEMM: C[M x N] = A[M x K] * WT[N x K]^T  (bf16 in, f32 acc)
// block 128x128 (4 waves 2x2, each 64x64). EPI: 0 plain f32 store (ldc),
// 1 t-path residual add into out, 2 b-path residual add.
template <int EPI>
__global__ __launch_bounds__(256) void gemm_mfma(const short* __restrict__ A,
                                                 const short* __restrict__ WT,
                                                 float* __restrict__ C,
                                                 int K, int ldc) {
  int w = threadIdx.x >> 6, lane = threadIdx.x & 63;
  int m0 = blockIdx.y * 128 + (w >> 1) * 64;
  int n0 = blockIdx.x * 128 + (w & 1) * 64;
  int lr = lane & 15, lg = lane >> 4;
  f32x4 acc[4][4];
#pragma unroll
  for (int i = 0; i < 4; ++i)
#pragma unroll
    for (int j = 0; j < 4; ++j) acc[i][j] = (f32x4){0.f, 0.f, 0.f, 0.f};
  const short* Ap = A + (long)(m0 + lr) * K + lg * 8;
  const short* Bp = WT + (long)(n0 + lr) * K + lg * 8;
#pragma unroll 2
  for (int k0 = 0; k0 < K; k0 += 32) {
    short8v a[4], b[4];
#pragma unroll
    for (int f = 0; f < 4; ++f) {
      a[f] = *(const short8v*)(Ap + (long)f * 16 * K + k0);
      b[f] = *(const short8v*)(Bp + (long)f * 16 * K + k0);
    }
#pragma unroll
    for (int i = 0; i < 4; ++i)
#pragma unroll
      for (int j = 0; j < 4; ++j)
        acc[i][j] = __builtin_amdgcn_mfma_f32_16x16x32_bf16(a[i], b[j], acc[i][j], 0, 0, 0);
  }
#pragma unroll
  for (int i = 0; i < 4; ++i)
#pragma unroll
    for (int j = 0; j < 4; ++j)
#pragma unroll
      for (int r = 0; r < 4; ++r) {
        int m = m0 + i * 16 + lg * 4 + r;
        int n = n0 + j * 16 + lr;
        if (EPI == 0) {
          C[(long)m * ldc + n] = acc[i][j][r];
        } else {
          long base = (EPI == 1) ? t_base(m) : (long)m * 256;
          C[base + n] += acc[i][j][r];
        }
      }
}

// ---------------- causal depthwise conv(K=4) + silu -> xBC[M x 640] bf16
// vectorized: 1 thread = 4 consecutive channels (float4 loads, short4 store)
__global__ __launch_bounds__(256) void k_conv(const float* __restrict__ zx,
                                              const float* __restrict__ Wc,
                                              const float* __restrict__ bc,
                                              short* __restrict__ xBC, int L) {
  int idx = blockIdx.x * 256 + threadIdx.x;
  if (idx >= MTOK * 160) return;
  int m = idx / 160, c4 = (idx - m * 160) << 2;
  int tpos = m % L;
  float4 w0 = *(const float4*)(Wc + (c4 + 0) * 4);
  float4 w1 = *(const float4*)(Wc + (c4 + 1) * 4);
  float4 w2 = *(const float4*)(Wc + (c4 + 2) * 4);
  float4 w3 = *(const float4*)(Wc + (c4 + 3) * 4);
  float4 acc = *(const float4*)(bc + c4);
  const float* base = zx + (long)m * PROJP + 512 + c4;
#pragma unroll
  for (int k = 0; k < 4; ++k) {
    int tt = tpos - 3 + k;
    if (tt >= 0) {
      float4 v = *(const float4*)(base + (long)(k - 3) * PROJP);
      acc.x += ((const float*)&w0)[k] * v.x;
      acc.y += ((const float*)&w1)[k] * v.y;
      acc.z += ((const float*)&w2)[k] * v.z;
      acc.w += ((const float*)&w3)[k] * v.w;
    }
  }
  short4v o;
  o[0] = f2bf(acc.x / (1.f + __expf(-acc.x)));
  o[1] = f2bf(acc.y / (1.f + __expf(-acc.y)));
  o[2] = f2bf(acc.z / (1.f + __expf(-acc.z)));
  o[3] = f2bf(acc.w / (1.f + __expf(-acc.w)));
  *(short4v*)(xBC + (long)m * 640 + c4) = o;
}

// ---------------- fused softplus(dt) + per-(seq,head) inclusive scan of dt*A
__global__ __launch_bounds__(256) void k_scan(const float* __restrict__ zx,
                                              const float* __restrict__ dtbias,
                                              const float* __restrict__ A_log,
                                              float* __restrict__ dtb,
                                              float* __restrict__ cumb,
                                              int nseq, int L) {
  int wid = blockIdx.x * 4 + (threadIdx.x >> 6);
  if (wid >= nseq * 8) return;
  int seq = wid >> 3, h = wid & 7, lane = threadIdx.x & 63;
  float Ah = -__expf(A_log[h]);
  float bias = dtbias[h];
  float run = 0.f;
  for (int t0 = 0; t0 < L; t0 += 64) {
    int tt = t0 + lane;
    float d = 0.f;
    if (tt < L) {
      float v = zx[((long)seq * L + tt) * PROJP + 1152 + h] + bias;
      d = (v > 20.f) ? v : log1pf(__expf(v));
    }
    float s = d * Ah;
#pragma unroll
    for (int off = 1; off < 64; off <<= 1) {
      float o = __shfl_up(s, off, 64);
      if (lane >= off) s += o;
    }
    if (tt < L) {
      long m = (long)seq * L + tt;
      dtb[m * 8 + h] = d;
      cumb[m * 8 + h] = run + s;
    }
    run += __shfl(s, 63, 64);
  }
}

// ---------------- x transpose: xT[(seq*8+h)*64 + p][LP] = x[s][h*64+p], zero-padded s>=L
template <int L>
__global__ __launch_bounds__(256) void k_xt(const short* __restrict__ xbc,
                                            short* __restrict__ xT) {
  constexpr int LP = (L + 63) & ~63;
  int seq = blockIdx.x, h = blockIdx.y, st = blockIdx.z;
  __shared__ short tile[64][72];
  int t = threadIdx.x;
  for (int e = t; e < 512; e += 256) {
    int s = e >> 3, p8 = (e & 7) * 8;
    int sg = st * 64 + s;
    union { short8v v; short a[8]; } u;
    if (sg < L) u.v = *(const short8v*)(xbc + ((long)seq * L + sg) * 640 + h * 64 + p8);
    else {
#pragma unroll
      for (int j = 0; j < 8; ++j) u.a[j] = 0;
    }
    *(short8v*)&tile[s][p8] = u.v;
  }
  __syncthreads();
  for (int e = t; e < 512; e += 256) {
    int p = e >> 3, s8 = (e & 7) * 8;
    union { short8v v; short a[8]; } u;
#pragma unroll
    for (int j = 0; j < 8; ++j) u.a[j] = tile[s8 + j][p];
    *(short8v*)(xT + ((long)(seq * 8 + h) * 64 + p) * LP + st * 64 + s8) = u.v;
  }
}

// ---------------- SSD v4: shared-CB, in-register P.
// Block = (hg, lt, seq), 4 waves. Phase A: waves cooperatively compute
// CB[64x64] = C_tile . B_chunk^T once (wave w does rows w*16..), store f32 to
// swizzled LDS. Phase B: wave w = head hg*4+w reads CB back in A-fragment
// layout, applies decay in registers (fwd s<=l: exp(cum_l-cum_s); rev s>=l:
// exp(cumP_s-cumP_l); diagonal twice), MFMAs against prefetched xT fragments.
template <int L, int NCH>
__global__ __launch_bounds__(256) void k_ssd4(const short* __restrict__ xbc,
                                              const short* __restrict__ xT,
                                              const float* __restrict__ dtb,
                                              const float* __restrict__ cumb,
                                              const float* __restrict__ A_log,
                                              short* __restrict__ y) {
  constexpr int LP = (L + 63) & ~63;
  constexpr bool FULL = (L % 64) == 0;
  int hg = blockIdx.x, lt = blockIdx.y, seq = blockIdx.z;
  int tid = threadIdx.x, w = tid >> 6, lane = tid & 63;
  int lr = lane & 15, lg = lane >> 4;
  int h = hg * 4 + w;
  int l0 = lt * 64;

  __shared__ float s_cb[64 * 64];     // [l][s ^ ((l&7)<<2)] f32, 16KB
  __shared__ float s_cums[64][8];     // cum for s-chunk, all heads
  __shared__ float s_dts[64][8];      // dt  for s-chunk, all heads

  float Ah = -__expf(A_log[h]);

  // l-side cum/dt for this wave's a-frag rows: l = l0 + i*16 + lr
  float cl[4], cpl[4];
#pragma unroll
  for (int i = 0; i < 4; ++i) {
    int lgl = l0 + i * 16 + lr;
    int lc = FULL ? lgl : (lgl < L ? lgl : L - 1);
    long m = (long)seq * L + lc;
    float cv = cumb[m * 8 + h];
    cl[i] = cv; cpl[i] = cv - dtb[m * 8 + h] * Ah;
  }

  f32x4 yacc[4][4];
#pragma unroll
  for (int i = 0; i < 4; ++i)
#pragma unroll
    for (int j = 0; j < 4; ++j) yacc[i][j] = (f32x4){0.f, 0.f, 0.f, 0.f};

  // phase-A A-operand rows: C rows l0 + w*16 + lr (clamped)
  int crow = l0 + w * 16 + lr;
  if (!FULL) crow = crow < L ? crow : L - 1;
  const short* Cp = xbc + ((long)seq * L + crow) * 640 + 576 + lg * 8;

  for (int c = 0; c < NCH; ++c) {
    int c64 = c * 64;

    // ---- stage s-side cum/dt (waves 0,1)
    if (tid < 128) {
      int r = tid & 63;
      int sg = c64 + r;
      int sc = FULL ? sg : (sg < L ? sg : L - 1);
      const float* src = (tid < 64 ? cumb : dtb) + ((long)seq * L + sc) * 8;
      float4 v0 = *(const float4*)(src);
      float4 v1 = *(const float4*)(src + 4);
      float* dstp = (tid < 64 ? &s_cums[r][0] : &s_dts[r][0]);
      *(float4*)dstp = v0;
      *(float4*)(dstp + 4) = v1;
    }

    // ---- phase A: CB rows [w*16, w*16+16) = C_rows . B_chunk^T
    f32x4 cb4[4];
#pragma unroll
    for (int j = 0; j < 4; ++j) cb4[j] = (f32x4){0.f, 0.f, 0.f, 0.f};
#pragma unroll
    for (int ks = 0; ks < 2; ++ks) {
      short8v a = *(const short8v*)(Cp + ks * 32);
#pragma unroll
      for (int j = 0; j < 4; ++j) {
        int srow = c64 + j * 16 + lr;
        if (!FULL) srow = srow < L ? srow : L - 1;
        short8v b = *(const short8v*)(xbc + ((long)seq * L + srow) * 640 + 512 + lg * 8 + ks * 32);
        cb4[j] = __builtin_amdgcn_mfma_f32_16x16x32_bf16(a, b, cb4[j], 0, 0, 0);
      }
    }
#pragma unroll
    for (int j = 0; j < 4; ++j)
#pragma unroll
      for (int r = 0; r < 4; ++r) {
        int lloc = w * 16 + lg * 4 + r;
        int sloc = j * 16 + lr;
        s_cb[lloc * 64 + (sloc ^ ((lloc & 7) << 2))] = cb4[j][r];
      }

    // ---- prefetch xT fragments for both k-steps (independent of LDS)
    short8v bx[2][4];
#pragma unroll
    for (int ks = 0; ks < 2; ++ks)
#pragma unroll
      for (int j = 0; j < 4; ++j)
        bx[ks][j] = *(const short8v*)(xT + ((long)(seq * 8 + h) * 64 + j * 16 + lr) * LP +
                                      c64 + ks * 32 + lg * 8);

    __syncthreads();  // CB + cum/dt staged

    // ---- phase B: decay in registers -> a-frag, MFMA with xT
#pragma unroll
    for (int ks = 0; ks < 2; ++ks) {
      int sbase = ks * 32 + lg * 8;
      float cs[8], cps[8], dss[8];
#pragma unroll
      for (int e = 0; e < 8; ++e) {
        int sl = sbase + e;
        float cv = s_cums[sl][h];
        float dv = s_dts[sl][h];
        cs[e] = cv; cps[e] = cv - dv * Ah; dss[e] = dv;
      }
#pragma unroll
      for (int i = 0; i < 4; ++i) {
        int R = i * 16 + lr;
        int lgl = l0 + R;
        int sw = (R & 7) << 2;
        int c0 = sbase ^ sw;
        const float* cbrow = &s_cb[R * 64];
        f32x4 lo = *(const f32x4*)(cbrow + c0);
        f32x4 hi = *(const f32x4*)(cbrow + (c0 ^ 4));
        short8v a;
#pragma unroll
        for (int e = 0; e < 8; ++e) {
          int sgl = c64 + sbase + e;
          float cbv = (e < 4) ? lo[e & 3] : hi[e & 3];
          float wgt = 0.f;
          if (sgl <= lgl) wgt += __expf(cl[i] - cs[e]);
          if (sgl >= lgl) wgt += __expf(cps[e] - cpl[i]);
          if (!FULL && (lgl >= L || sgl >= L)) wgt = 0.f;
          a[e] = f2bf(cbv * wgt * dss[e]);
        }
#pragma unroll
        for (int j = 0; j < 4; ++j)
          yacc[i][j] = __builtin_amdgcn_mfma_f32_16x16x32_bf16(a, bx[ks][j], yacc[i][j], 0, 0, 0);
      }
    }
    if (c + 1 < NCH) __syncthreads();  // done reading s_cb before overwrite
  }

  // store y (bf16): rows l0 + i*16 + lg*4 + r, cols h*64 + j*16 + lr
#pragma unroll
  for (int i = 0; i < 4; ++i)
#pragma unroll
    for (int r = 0; r < 4; ++r) {
      int lgl = l0 + i * 16 + lg * 4 + r;
      if (FULL || lgl < L) {
        short* yp = y + ((long)seq * L + lgl) * 512 + h * 64 + lr;
#pragma unroll
        for (int j = 0; j < 4; ++j) yp[j * 16] = f2bf(yacc[i][j][r]);
      }
    }
}

// ---------------- gate: ybh = rmsnorm((y + D*xh) * silu(z)) * gn_w  (bf16 out)
__global__ __launch_bounds__(256) void k_gate2(const short* __restrict__ y,
                                               const float* __restrict__ zx,
                                               const short* __restrict__ xbc,
                                               const float* __restrict__ Dp,
                                               const float* __restrict__ gnw,
                                               short* __restrict__ ybh) {
  int m = blockIdx.x * 4 + (threadIdx.x >> 6);
  int lane = threadIdx.x & 63;
  int d0 = lane * 8;
  short8v yv = *(const short8v*)(y + (long)m * 512 + d0);
  short8v xv = *(const short8v*)(xbc + (long)m * 640 + d0);
  float4 za = *(const float4*)(zx + (long)m * PROJP + d0);
  float4 zb = *(const float4*)(zx + (long)m * PROJP + d0 + 4);
  float Dh = Dp[lane >> 3];
  float zf[8] = {za.x, za.y, za.z, za.w, zb.x, zb.y, zb.z, zb.w};
  float g[8];
  float ss = 0.f;
#pragma unroll
  for (int i = 0; i < 8; ++i) {
    float zi = zf[i];
    g[i] = (bf2f(yv[i]) + Dh * bf2f(xv[i])) * zi / (1.f + __expf(-zi));
    ss += g[i] * g[i];
  }
  ss = wave_sum64(ss);
  float scl = rsqrtf(ss * (1.f / 512.f) + 1e-6f);
  short8v o;
#pragma unroll
  for (int i = 0; i < 8; ++i) o[i] = f2bf(g[i] * scl * gnw[d0 + i]);
  *(short8v*)(ybh + (long)m * 512 + d0) = o;
}

extern "C" void kernel_launch(void* const* d_in, const int* in_sizes, int n_in,
                              void* d_out, int out_size, void* d_ws, size_t ws_size,
                              hipStream_t stream) {
  (void)in_sizes; (void)n_in; (void)out_size; (void)ws_size;
  const float* x = (const float*)d_in[0];
  float* out = (float*)d_out;
  const long M = MTOK;

  char* p = (char*)d_ws;
  float* zx = (float*)p;     p += (size_t)M * PROJP * 4;       // 121.9 MB
  short* bufn = (short*)p;   p += (size_t)M * 256 * 2;         // 12.2 MB
  short* xbc = (short*)p;    p += (size_t)M * 640 * 2 + 4096;  // 30.5 MB
  float* dtb = (float*)p;    p += (size_t)M * 8 * 4;
  float* cumb = (float*)p;   p += (size_t)M * 8 * 4;
  short* ybuf = (short*)p;   p += (size_t)M * 512 * 2;         // 24.4 MB
  short* xT = (short*)p;     p += (size_t)12582912 * 2;        // 25.2 MB
  short* ybh = (short*)p;    p += (size_t)M * 512 * 2;         // 24.4 MB
  short* WinT = (short*)p;   p += (size_t)4 * PROJP * 256 * 2; // 2.6 MB
  short* WoutT = (short*)p;  p += (size_t)4 * 256 * 512 * 2;   // 1.0 MB

  // weight prep (every call; deterministic)
  k_wt<<<dim3((PROJP * 256 + 255) / 256, 1, 4), 256, 0, stream>>>(
      (const float*)d_in[2], (const float*)d_in[11], WinT, 256, 1160, PROJP);
  k_wt<<<dim3((256 * 512 + 255) / 256, 1, 4), 256, 0, stream>>>(
      (const float*)d_in[9], (const float*)d_in[18], WoutT, 512, 256, 256);

  hipMemcpyAsync(out, x, (size_t)M * 256 * sizeof(float), hipMemcpyDeviceToDevice, stream);

  for (int layer = 0; layer < 2; ++layer) {
    for (int path = 0; path < 2; ++path) {
      const float* const* P = (const float* const*)(d_in + 1 + path * 9);
      const float* nw = P[0] + layer * 256;
      const float* Wc = P[2] + layer * 640 * 4;
      const float* bc = P[3] + layer * 640;
      const float* dtbias = P[4] + layer * 8;
      const float* Alog = P[5] + layer * 8;
      const float* Dp = P[6] + layer * 8;
      const float* gnw = P[7] + layer * 512;
      const short* WinTp = WinT + (long)(path * 2 + layer) * PROJP * 256;
      const short* WoutTp = WoutT + (long)(path * 2 + layer) * 256 * 512;
      int L = (path == 0) ? 192 : 62;
      int nseq = (path == 0) ? 124 : 384;

      if (path == 0) k_rmsnorm_in<true><<<MTOK / 4, 256, 0, stream>>>(out, nw, bufn);
      else           k_rmsnorm_in<false><<<MTOK / 4, 256, 0, stream>>>(out, nw, bufn);

      gemm_mfma<0><<<dim3(PROJP / 128, MTOK / 128), 256, 0, stream>>>(bufn, WinTp, zx, 256, PROJP);

      k_conv<<<(MTOK * 160 + 255) / 256, 256, 0, stream>>>(zx, Wc, bc, xbc, L);
      k_scan<<<(nseq * 8 + 3) / 4, 256, 0, stream>>>(zx, dtbias, Alog, dtb, cumb, nseq, L);

      if (path == 0) k_xt<192><<<dim3(nseq, 8, 3), 256, 0, stream>>>(xbc, xT);
      else           k_xt<62><<<dim3(nseq, 8, 1), 256, 0, stream>>>(xbc, xT);

      if (path == 0) k_ssd4<192, 3><<<dim3(2, 3, nseq), 256, 0, stream>>>(xbc, xT, dtb, cumb, Alog, ybuf);
      else           k_ssd4<62, 1><<<dim3(2, 1, nseq), 256, 0, stream>>>(xbc, xT, dtb, cumb, Alog, ybuf);

      k_gate2<<<MTOK / 4, 256, 0, stream>>>(ybuf, zx, xbc, Dp, gnw, ybh);

      if (path == 0) gemm_mfma<1><<<dim3(2, MTOK / 128), 256, 0, stream>>>(ybh, WoutTp, out, 512, 0);
      else           gemm_mfma<2><<<dim3(2, MTOK / 128), 256, 0, stream>>>(ybh, WoutTp, out, 512, 0);
    }
  }
}